// Round 4
// baseline (423.145 us; speedup 1.0000x reference)
//
#include <hip/hip_runtime.h>
#include <stdint.h>

typedef __attribute__((ext_vector_type(8))) short short8;
typedef __attribute__((ext_vector_type(4))) float floatx4;
typedef __attribute__((ext_vector_type(4))) unsigned int uint4v;
typedef __attribute__((ext_vector_type(2))) unsigned int uint2v;

#define NSEQ 8
#define BLKSZ 16
#define NBLK_PER_SEQ 128
#define HQN 32
#define HKVN 8
#define GQ 4
#define HD 128
#define WINDOW 1024
#define SCALE 0.08838834764831845f

#define QB 32       // q rows per block (4 waves = 4 GQA heads share K/V)
#define KVB 64      // kv tile

#define MFMA16 __builtin_amdgcn_mfma_f32_16x16x32_bf16

// two f32 -> packed bf16x2 (round-half-up) via one v_perm
static __device__ __forceinline__ unsigned int pack2bf(float lo, float hi) {
    unsigned int a = __builtin_bit_cast(unsigned int, lo) + 0x8000u;
    unsigned int b = __builtin_bit_cast(unsigned int, hi) + 0x8000u;
    return __builtin_amdgcn_perm(b, a, 0x07060302u);  // low16 = lo>>16, high16 = hi>>16
}
static __device__ __forceinline__ short f2bf(float x) {
    return (short)((__builtin_bit_cast(unsigned int, x) + 0x8000u) >> 16);
}

// DPP row_ror reduction step (within 16-lane rows) — VALU, not LDS pipe
#define ROR_F(x, n) __builtin_bit_cast(float, __builtin_amdgcn_update_dpp( \
    __builtin_bit_cast(int, x), __builtin_bit_cast(int, x), 0x120 | (n), 0xf, 0xf, false))

__global__ __launch_bounds__(256, 3)
void attn_fwd(const float* __restrict__ qg,
              const float* __restrict__ kg,
              const float* __restrict__ vg,
              const int* __restrict__ bt,
              const int* __restrict__ seqlens,
              const int* __restrict__ qsl,
              float* __restrict__ outg)
{
    // XOR-swizzled (byte ^= (row&7)<<4), no pads: 48 KiB total -> 3 blocks/CU
    __shared__ __align__(16) short Klds[KVB][128];     // 16384 B
    __shared__ __align__(16) short Vt[HD][KVB];        // 16384 B  (V^T: [d][kv])
    __shared__ __align__(16) short Plds[4][QB][KVB];   // 16384 B

    const int tid  = threadIdx.x;
    const int wave = tid >> 6;
    const int lane = tid & 63;
    const int l15  = lane & 15;
    const int lg   = lane >> 4;

    // XCD pinning: consecutive block ids round-robin XCDs -> b&7 = kv head
    const int b  = blockIdx.x;
    const int h  = b & 7;
    const int qt = (b >> 3) & 7;
    const int s  = b >> 6;
    const int q0 = qt * QB;

    const int qstart = qsl[s];
    const int numq   = qsl[s + 1] - qstart;
    const int slen   = seqlens[s];
    const int ctx    = slen - numq;
    const int hq     = h * GQ + wave;

    // ---- Q fragments (A-operand), pre-scaled by SCALE ----
    short8 qf[2][4];
    #pragma unroll
    for (int mt = 0; mt < 2; ++mt) {
        const float* qrow = qg + ((size_t)(qstart + q0 + mt * 16 + l15) * HQN + hq) * HD;
        #pragma unroll
        for (int kt = 0; kt < 4; ++kt) {
            floatx4 f0 = *(const floatx4*)(qrow + kt * 32 + lg * 8);
            floatx4 f1 = *(const floatx4*)(qrow + kt * 32 + lg * 8 + 4);
            uint4v w;
            w[0] = pack2bf(f0[0] * SCALE, f0[1] * SCALE);
            w[1] = pack2bf(f0[2] * SCALE, f0[3] * SCALE);
            w[2] = pack2bf(f1[0] * SCALE, f1[1] * SCALE);
            w[3] = pack2bf(f1[2] * SCALE, f1[3] * SCALE);
            qf[mt][kt] = __builtin_bit_cast(short8, w);
        }
    }

    floatx4 oacc[2][8];
    #pragma unroll
    for (int mt = 0; mt < 2; ++mt)
        #pragma unroll
        for (int n = 0; n < 8; ++n)
            oacc[mt][n] = (floatx4){0.f, 0.f, 0.f, 0.f};

    float mrun[2][4], lrun[2][4];
    #pragma unroll
    for (int mt = 0; mt < 2; ++mt)
        #pragma unroll
        for (int r = 0; r < 4; ++r) { mrun[mt][r] = -INFINITY; lrun[mt][r] = 0.f; }

    int lo = ctx + q0 - WINDOW + 1; if (lo < 0) lo = 0;
    int hi = ctx + q0 + QB - 1;     if (hi > slen - 1) hi = slen - 1;
    const int t0 = lo / KVB, t1 = hi / KVB;

    // staging maps
    const int srow = tid >> 3;          // K: kv row 0..31 (+32 for p=1)
    const int kc0  = (tid & 7) * 32;    // K: byte col (16 d-values = 32B)
    const int v4   = tid & 15;          // V: kv group (4 rows 4v4..4v4+3)
    const int dblk = tid >> 4;          // V: d block (8 d-values)

    floatx4 fk[8], fA[4], fB[4];        // raw f32 for next tile (T14 async split)

    // prologue: load tile t0
    {
        const int kv0 = t0 * KVB;
        #pragma unroll
        for (int p = 0; p < 2; ++p) {
            const int kvp = kv0 + p * 32 + srow;
            const int blk = bt[s * NBLK_PER_SEQ + (kvp >> 4)];
            const float* src = kg + (((size_t)blk * BLKSZ + (kvp & 15)) * HKVN + h) * HD + (tid & 7) * 16;
            fk[p*4+0] = *(const floatx4*)(src);
            fk[p*4+1] = *(const floatx4*)(src + 4);
            fk[p*4+2] = *(const floatx4*)(src + 8);
            fk[p*4+3] = *(const floatx4*)(src + 12);
        }
        const int kvv = kv0 + 4 * v4;
        const int blk = bt[s * NBLK_PER_SEQ + (kvv >> 4)];   // 4v4..4v4+3 same block
        const float* src = vg + (((size_t)blk * BLKSZ + (kvv & 15)) * HKVN + h) * HD + dblk * 8;
        #pragma unroll
        for (int r = 0; r < 4; ++r) {
            fA[r] = *(const floatx4*)(src + (size_t)r * HKVN * HD);
            fB[r] = *(const floatx4*)(src + (size_t)r * HKVN * HD + 4);
        }
    }

    for (int t = t0; t <= t1; ++t) {
        const int kv0 = t * KVB;
        __syncthreads();   // all waves done with previous tile's LDS

        // ---- convert + store tile t ----
        #pragma unroll
        for (int p = 0; p < 2; ++p) {
            const int row = p * 32 + srow;
            char* kb = (char*)Klds + row * 256;
            const int c = kc0 ^ ((row & 7) << 4);
            uint4v w;
            w[0] = pack2bf(fk[p*4+0][0], fk[p*4+0][1]);
            w[1] = pack2bf(fk[p*4+0][2], fk[p*4+0][3]);
            w[2] = pack2bf(fk[p*4+1][0], fk[p*4+1][1]);
            w[3] = pack2bf(fk[p*4+1][2], fk[p*4+1][3]);
            *(uint4v*)(kb + c) = w;
            w[0] = pack2bf(fk[p*4+2][0], fk[p*4+2][1]);
            w[1] = pack2bf(fk[p*4+2][2], fk[p*4+2][3]);
            w[2] = pack2bf(fk[p*4+3][0], fk[p*4+3][1]);
            w[3] = pack2bf(fk[p*4+3][2], fk[p*4+3][3]);
            *(uint4v*)(kb + (c ^ 16)) = w;
        }
        {
            char* vb = (char*)Vt + dblk * 1024;
            #pragma unroll
            for (int i = 0; i < 8; ++i) {
                uint2v w;
                if (i < 4) { w[0] = pack2bf(fA[0][i], fA[1][i]);
                             w[1] = pack2bf(fA[2][i], fA[3][i]); }
                else       { w[0] = pack2bf(fB[0][i-4], fB[1][i-4]);
                             w[1] = pack2bf(fB[2][i-4], fB[3][i-4]); }
                *(uint2v*)(vb + i * 128 + ((v4 * 8) ^ (i << 4))) = w;
            }
        }
        __syncthreads();

        // ---- QK^T: S[q][kv] ----
        floatx4 sacc[2][4];
        #pragma unroll
        for (int mt = 0; mt < 2; ++mt)
            #pragma unroll
            for (int nt = 0; nt < 4; ++nt)
                sacc[mt][nt] = (floatx4){0.f, 0.f, 0.f, 0.f};
        const int kswz = (l15 & 7) << 4;
        #pragma unroll
        for (int kt = 0; kt < 4; ++kt) {
            #pragma unroll
            for (int nt = 0; nt < 4; ++nt) {
                short8 kf = *(const short8*)((char*)Klds + (nt * 16 + l15) * 256
                                             + ((kt * 64 + lg * 16) ^ kswz));
                sacc[0][nt] = MFMA16(qf[0][kt], kf, sacc[0][nt], 0, 0, 0);
                sacc[1][nt] = MFMA16(qf[1][kt], kf, sacc[1][nt], 0, 0, 0);
            }
        }

        // ---- issue next tile's global loads (overlap with softmax+PV) ----
        if (t < t1) {
            const int kv0n = kv0 + KVB;
            #pragma unroll
            for (int p = 0; p < 2; ++p) {
                const int kvp = kv0n + p * 32 + srow;
                const int blk = bt[s * NBLK_PER_SEQ + (kvp >> 4)];
                const float* src = kg + (((size_t)blk * BLKSZ + (kvp & 15)) * HKVN + h) * HD + (tid & 7) * 16;
                fk[p*4+0] = *(const floatx4*)(src);
                fk[p*4+1] = *(const floatx4*)(src + 4);
                fk[p*4+2] = *(const floatx4*)(src + 8);
                fk[p*4+3] = *(const floatx4*)(src + 12);
            }
            const int kvv = kv0n + 4 * v4;
            const int blk = bt[s * NBLK_PER_SEQ + (kvv >> 4)];
            const float* src = vg + (((size_t)blk * BLKSZ + (kvv & 15)) * HKVN + h) * HD + dblk * 8;
            #pragma unroll
            for (int r = 0; r < 4; ++r) {
                fA[r] = *(const floatx4*)(src + (size_t)r * HKVN * HD);
                fB[r] = *(const floatx4*)(src + (size_t)r * HKVN * HD + 4);
            }
        }

        // ---- online softmax (per q-row), DPP reductions, defer-max ----
        const bool interior = (kv0 >= ctx + q0 - (WINDOW - QB)) &&
                              (kv0 + KVB - 1 <= ctx + q0);
        char* pbase = (char*)Plds + wave * (QB * KVB * 2);
        #pragma unroll
        for (int mt = 0; mt < 2; ++mt) {
            #pragma unroll
            for (int r = 0; r < 4; ++r) {
                float sv[4];
                if (interior) {
                    #pragma unroll
                    for (int nt = 0; nt < 4; ++nt) sv[nt] = sacc[mt][nt][r];
                } else {
                    const int qpos = ctx + q0 + mt * 16 + lg * 4 + r;
                    #pragma unroll
                    for (int nt = 0; nt < 4; ++nt) {
                        const int kpos = kv0 + nt * 16 + l15;
                        const bool valid = (kpos <= qpos) && (qpos - kpos < WINDOW);
                        sv[nt] = valid ? sacc[mt][nt][r] : -INFINITY;
                    }
                }
                float rmax = fmaxf(fmaxf(sv[0], sv[1]), fmaxf(sv[2], sv[3]));
                rmax = fmaxf(rmax, ROR_F(rmax, 8));
                rmax = fmaxf(rmax, ROR_F(rmax, 4));
                rmax = fmaxf(rmax, ROR_F(rmax, 2));
                rmax = fmaxf(rmax, ROR_F(rmax, 1));
                const float mold = mrun[mt][r];
                const bool defer = __all(rmax <= mold + 8.0f);
                const float mnew = defer ? mold : fmaxf(mold, rmax);
                const float alpha = defer ? 1.0f
                    : ((mnew == -INFINITY) ? 1.0f : __expf(mold - mnew));
                const bool dead = (mnew == -INFINITY);
                float e[4], rsum = 0.f;
                #pragma unroll
                for (int nt = 0; nt < 4; ++nt) {
                    e[nt] = dead ? 0.f : __expf(sv[nt] - mnew);
                    rsum += e[nt];
                }
                rsum += ROR_F(rsum, 8);
                rsum += ROR_F(rsum, 4);
                rsum += ROR_F(rsum, 2);
                rsum += ROR_F(rsum, 1);
                lrun[mt][r] = lrun[mt][r] * alpha + rsum;
                mrun[mt][r] = mnew;
                if (alpha != 1.0f) {
                    #pragma unroll
                    for (int n = 0; n < 8; ++n) oacc[mt][n][r] *= alpha;
                }
                const int prow = mt * 16 + lg * 4 + r;
                char* pr = pbase + prow * 128;
                const int pswz = (prow & 7) << 4;
                #pragma unroll
                for (int nt = 0; nt < 4; ++nt)
                    *(short*)(pr + ((nt * 32 + l15 * 2) ^ pswz)) = f2bf(e[nt]);
            }
        }

        // ---- PV: O += P @ V ----
        #pragma unroll
        for (int ks = 0; ks < 2; ++ks) {
            short8 pf0 = *(const short8*)(pbase + l15 * 128
                                          + ((ks * 64 + lg * 16) ^ kswz));
            short8 pf1 = *(const short8*)(pbase + (16 + l15) * 128
                                          + ((ks * 64 + lg * 16) ^ kswz));
            #pragma unroll
            for (int n = 0; n < 8; ++n) {
                short8 vfn = *(const short8*)((char*)Vt + (n * 16 + l15) * 128
                                              + ((ks * 64 + lg * 16) ^ kswz));
                oacc[0][n] = MFMA16(pf0, vfn, oacc[0][n], 0, 0, 0);
                oacc[1][n] = MFMA16(pf1, vfn, oacc[1][n], 0, 0, 0);
            }
        }
    }

    // ---- epilogue ----
    #pragma unroll
    for (int mt = 0; mt < 2; ++mt) {
        #pragma unroll
        for (int r = 0; r < 4; ++r) {
            const float inv = 1.0f / lrun[mt][r];
            const int qi = q0 + mt * 16 + lg * 4 + r;
            float* orow = outg + ((size_t)(qstart + qi) * HQN + hq) * HD + l15;
            #pragma unroll
            for (int n = 0; n < 8; ++n)
                orow[n * 16] = oacc[mt][n][r] * inv;
        }
    }
}

extern "C" void kernel_launch(void* const* d_in, const int* in_sizes, int n_in,
                              void* d_out, int out_size, void* d_ws, size_t ws_size,
                              hipStream_t stream) {
    const float* q  = (const float*)d_in[0];
    const float* k  = (const float*)d_in[1];
    const float* v  = (const float*)d_in[2];
    const int* btp  = (const int*)d_in[3];
    const int* sl   = (const int*)d_in[4];
    const int* qs   = (const int*)d_in[5];
    float* out      = (float*)d_out;

    attn_fwd<<<dim3(NSEQ * HKVN * 8), 256, 0, stream>>>(q, k, v, btp, sl, qs, out);
}

// Round 5
// 224.117 us; speedup vs baseline: 1.8881x; 1.8881x over previous
//
#include <hip/hip_runtime.h>
#include <stdint.h>

typedef __attribute__((ext_vector_type(8))) short short8;
typedef __attribute__((ext_vector_type(4))) float floatx4;
typedef __attribute__((ext_vector_type(4))) unsigned int uint4v;
typedef __attribute__((ext_vector_type(2))) unsigned int uint2v;

#define NSEQ 8
#define BLKSZ 16
#define NBLK_PER_SEQ 128
#define HQN 32
#define HKVN 8
#define GQ 4
#define HD 128
#define WINDOW 1024
#define SCALE 0.08838834764831845f

#define QB 32       // q rows per block (4 waves = 4 GQA heads share K/V)
#define KVB 64      // kv tile

#define MFMA16 __builtin_amdgcn_mfma_f32_16x16x32_bf16

// two f32 -> packed bf16x2 (round-half-up) via one v_perm
static __device__ __forceinline__ unsigned int pack2bf(float lo, float hi) {
    unsigned int a = __builtin_bit_cast(unsigned int, lo) + 0x8000u;
    unsigned int b = __builtin_bit_cast(unsigned int, hi) + 0x8000u;
    return __builtin_amdgcn_perm(b, a, 0x07060302u);  // low16 = lo>>16, high16 = hi>>16
}
static __device__ __forceinline__ short f2bf(float x) {
    return (short)((__builtin_bit_cast(unsigned int, x) + 0x8000u) >> 16);
}

// DPP row_ror reduction step (within 16-lane rows) — VALU, not LDS pipe
#define ROR_F(x, n) __builtin_bit_cast(float, __builtin_amdgcn_update_dpp( \
    __builtin_bit_cast(int, x), __builtin_bit_cast(int, x), 0x120 | (n), 0xf, 0xf, false))

__global__ __launch_bounds__(256, 2)
void attn_fwd(const float* __restrict__ qg,
              const float* __restrict__ kg,
              const float* __restrict__ vg,
              const int* __restrict__ bt,
              const int* __restrict__ seqlens,
              const int* __restrict__ qsl,
              float* __restrict__ outg)
{
    // XOR-swizzled (byte ^= (row&7)<<4), no pads: 48 KiB total -> 3 blocks/CU
    __shared__ __align__(16) short Klds[KVB][128];     // 16384 B
    __shared__ __align__(16) short Vt[HD][KVB];        // 16384 B  (V^T: [d][kv])
    __shared__ __align__(16) short Plds[4][QB][KVB];   // 16384 B

    const int tid  = threadIdx.x;
    const int wave = tid >> 6;
    const int lane = tid & 63;
    const int l15  = lane & 15;
    const int lg   = lane >> 4;

    // XCD pinning: consecutive block ids round-robin XCDs -> b&7 = kv head
    const int b  = blockIdx.x;
    const int h  = b & 7;
    const int qt = (b >> 3) & 7;
    const int s  = b >> 6;
    const int q0 = qt * QB;

    const int qstart = qsl[s];
    const int numq   = qsl[s + 1] - qstart;
    const int slen   = seqlens[s];
    const int ctx    = slen - numq;
    const int hq     = h * GQ + wave;

    // ---- Q fragments (A-operand), pre-scaled by SCALE ----
    short8 qf[2][4];
    #pragma unroll
    for (int mt = 0; mt < 2; ++mt) {
        const float* qrow = qg + ((size_t)(qstart + q0 + mt * 16 + l15) * HQN + hq) * HD;
        #pragma unroll
        for (int kt = 0; kt < 4; ++kt) {
            floatx4 f0 = *(const floatx4*)(qrow + kt * 32 + lg * 8);
            floatx4 f1 = *(const floatx4*)(qrow + kt * 32 + lg * 8 + 4);
            uint4v w;
            w[0] = pack2bf(f0[0] * SCALE, f0[1] * SCALE);
            w[1] = pack2bf(f0[2] * SCALE, f0[3] * SCALE);
            w[2] = pack2bf(f1[0] * SCALE, f1[1] * SCALE);
            w[3] = pack2bf(f1[2] * SCALE, f1[3] * SCALE);
            qf[mt][kt] = __builtin_bit_cast(short8, w);
        }
    }

    floatx4 oacc[2][8];
    #pragma unroll
    for (int mt = 0; mt < 2; ++mt)
        #pragma unroll
        for (int n = 0; n < 8; ++n)
            oacc[mt][n] = (floatx4){0.f, 0.f, 0.f, 0.f};

    float mrun[2][4], lrun[2][4];
    #pragma unroll
    for (int mt = 0; mt < 2; ++mt)
        #pragma unroll
        for (int r = 0; r < 4; ++r) { mrun[mt][r] = -INFINITY; lrun[mt][r] = 0.f; }

    int lo = ctx + q0 - WINDOW + 1; if (lo < 0) lo = 0;
    int hi = ctx + q0 + QB - 1;     if (hi > slen - 1) hi = slen - 1;
    const int t0 = lo / KVB, t1 = hi / KVB;

    // staging maps
    const int srow = tid >> 3;          // K: kv row 0..31 (+32 for p=1)
    const int kc0  = (tid & 7) * 32;    // K: byte col (16 d-values = 32B)
    const int v4   = tid & 15;          // V: kv group (4 rows 4v4..4v4+3)
    const int dblk = tid >> 4;          // V: d block (8 d-values)

    floatx4 fk[8], fA[4], fB[4];        // raw f32 for next tile (T14 async split)

    // prologue: load tile t0
    {
        const int kv0 = t0 * KVB;
        #pragma unroll
        for (int p = 0; p < 2; ++p) {
            const int kvp = kv0 + p * 32 + srow;
            const int blk = bt[s * NBLK_PER_SEQ + (kvp >> 4)];
            const float* src = kg + (((size_t)blk * BLKSZ + (kvp & 15)) * HKVN + h) * HD + (tid & 7) * 16;
            fk[p*4+0] = *(const floatx4*)(src);
            fk[p*4+1] = *(const floatx4*)(src + 4);
            fk[p*4+2] = *(const floatx4*)(src + 8);
            fk[p*4+3] = *(const floatx4*)(src + 12);
        }
        const int kvv = kv0 + 4 * v4;
        const int blk = bt[s * NBLK_PER_SEQ + (kvv >> 4)];   // 4v4..4v4+3 same block
        const float* src = vg + (((size_t)blk * BLKSZ + (kvv & 15)) * HKVN + h) * HD + dblk * 8;
        #pragma unroll
        for (int r = 0; r < 4; ++r) {
            fA[r] = *(const floatx4*)(src + (size_t)r * HKVN * HD);
            fB[r] = *(const floatx4*)(src + (size_t)r * HKVN * HD + 4);
        }
    }

    for (int t = t0; t <= t1; ++t) {
        const int kv0 = t * KVB;
        __syncthreads();   // all waves done with previous tile's LDS

        // ---- convert + store tile t ----
        #pragma unroll
        for (int p = 0; p < 2; ++p) {
            const int row = p * 32 + srow;
            char* kb = (char*)Klds + row * 256;
            const int c = kc0 ^ ((row & 7) << 4);
            uint4v w;
            w[0] = pack2bf(fk[p*4+0][0], fk[p*4+0][1]);
            w[1] = pack2bf(fk[p*4+0][2], fk[p*4+0][3]);
            w[2] = pack2bf(fk[p*4+1][0], fk[p*4+1][1]);
            w[3] = pack2bf(fk[p*4+1][2], fk[p*4+1][3]);
            *(uint4v*)(kb + c) = w;
            w[0] = pack2bf(fk[p*4+2][0], fk[p*4+2][1]);
            w[1] = pack2bf(fk[p*4+2][2], fk[p*4+2][3]);
            w[2] = pack2bf(fk[p*4+3][0], fk[p*4+3][1]);
            w[3] = pack2bf(fk[p*4+3][2], fk[p*4+3][3]);
            *(uint4v*)(kb + (c ^ 16)) = w;
        }
        {
            char* vb = (char*)Vt + dblk * 1024;
            #pragma unroll
            for (int i = 0; i < 8; ++i) {
                uint2v w;
                if (i < 4) { w[0] = pack2bf(fA[0][i], fA[1][i]);
                             w[1] = pack2bf(fA[2][i], fA[3][i]); }
                else       { w[0] = pack2bf(fB[0][i-4], fB[1][i-4]);
                             w[1] = pack2bf(fB[2][i-4], fB[3][i-4]); }
                *(uint2v*)(vb + i * 128 + ((v4 * 8) ^ (i << 4))) = w;
            }
        }
        __syncthreads();

        // ---- QK^T: S[q][kv] ----
        floatx4 sacc[2][4];
        #pragma unroll
        for (int mt = 0; mt < 2; ++mt)
            #pragma unroll
            for (int nt = 0; nt < 4; ++nt)
                sacc[mt][nt] = (floatx4){0.f, 0.f, 0.f, 0.f};
        const int kswz = (l15 & 7) << 4;
        #pragma unroll
        for (int kt = 0; kt < 4; ++kt) {
            #pragma unroll
            for (int nt = 0; nt < 4; ++nt) {
                short8 kf = *(const short8*)((char*)Klds + (nt * 16 + l15) * 256
                                             + ((kt * 64 + lg * 16) ^ kswz));
                sacc[0][nt] = MFMA16(qf[0][kt], kf, sacc[0][nt], 0, 0, 0);
                sacc[1][nt] = MFMA16(qf[1][kt], kf, sacc[1][nt], 0, 0, 0);
            }
        }

        // ---- issue next tile's global loads (overlap with softmax+PV) ----
        if (t < t1) {
            const int kv0n = kv0 + KVB;
            #pragma unroll
            for (int p = 0; p < 2; ++p) {
                const int kvp = kv0n + p * 32 + srow;
                const int blk = bt[s * NBLK_PER_SEQ + (kvp >> 4)];
                const float* src = kg + (((size_t)blk * BLKSZ + (kvp & 15)) * HKVN + h) * HD + (tid & 7) * 16;
                fk[p*4+0] = *(const floatx4*)(src);
                fk[p*4+1] = *(const floatx4*)(src + 4);
                fk[p*4+2] = *(const floatx4*)(src + 8);
                fk[p*4+3] = *(const floatx4*)(src + 12);
            }
            const int kvv = kv0n + 4 * v4;
            const int blk = bt[s * NBLK_PER_SEQ + (kvv >> 4)];
            const float* src = vg + (((size_t)blk * BLKSZ + (kvv & 15)) * HKVN + h) * HD + dblk * 8;
            #pragma unroll
            for (int r = 0; r < 4; ++r) {
                fA[r] = *(const floatx4*)(src + (size_t)r * HKVN * HD);
                fB[r] = *(const floatx4*)(src + (size_t)r * HKVN * HD + 4);
            }
        }

        // ---- online softmax (per q-row), DPP reductions, defer-max ----
        const bool interior = (kv0 >= ctx + q0 - (WINDOW - QB)) &&
                              (kv0 + KVB - 1 <= ctx + q0);
        char* pbase = (char*)Plds + wave * (QB * KVB * 2);
        #pragma unroll
        for (int mt = 0; mt < 2; ++mt) {
            #pragma unroll
            for (int r = 0; r < 4; ++r) {
                float sv[4];
                if (interior) {
                    #pragma unroll
                    for (int nt = 0; nt < 4; ++nt) sv[nt] = sacc[mt][nt][r];
                } else {
                    const int qpos = ctx + q0 + mt * 16 + lg * 4 + r;
                    #pragma unroll
                    for (int nt = 0; nt < 4; ++nt) {
                        const int kpos = kv0 + nt * 16 + l15;
                        const bool valid = (kpos <= qpos) && (qpos - kpos < WINDOW);
                        sv[nt] = valid ? sacc[mt][nt][r] : -INFINITY;
                    }
                }
                float rmax = fmaxf(fmaxf(sv[0], sv[1]), fmaxf(sv[2], sv[3]));
                rmax = fmaxf(rmax, ROR_F(rmax, 8));
                rmax = fmaxf(rmax, ROR_F(rmax, 4));
                rmax = fmaxf(rmax, ROR_F(rmax, 2));
                rmax = fmaxf(rmax, ROR_F(rmax, 1));
                const float mold = mrun[mt][r];
                const bool defer = __all(rmax <= mold + 8.0f);
                const float mnew = defer ? mold : fmaxf(mold, rmax);
                const float alpha = defer ? 1.0f
                    : ((mnew == -INFINITY) ? 1.0f : __expf(mold - mnew));
                const bool dead = (mnew == -INFINITY);
                float e[4], rsum = 0.f;
                #pragma unroll
                for (int nt = 0; nt < 4; ++nt) {
                    e[nt] = dead ? 0.f : __expf(sv[nt] - mnew);
                    rsum += e[nt];
                }
                rsum += ROR_F(rsum, 8);
                rsum += ROR_F(rsum, 4);
                rsum += ROR_F(rsum, 2);
                rsum += ROR_F(rsum, 1);
                lrun[mt][r] = lrun[mt][r] * alpha + rsum;
                mrun[mt][r] = mnew;
                if (alpha != 1.0f) {
                    #pragma unroll
                    for (int n = 0; n < 8; ++n) oacc[mt][n][r] *= alpha;
                }
                const int prow = mt * 16 + lg * 4 + r;
                char* pr = pbase + prow * 128;
                const int pswz = (prow & 7) << 4;
                #pragma unroll
                for (int nt = 0; nt < 4; ++nt)
                    *(short*)(pr + ((nt * 32 + l15 * 2) ^ pswz)) = f2bf(e[nt]);
            }
        }

        // ---- PV: O += P @ V ----
        #pragma unroll
        for (int ks = 0; ks < 2; ++ks) {
            short8 pf0 = *(const short8*)(pbase + l15 * 128
                                          + ((ks * 64 + lg * 16) ^ kswz));
            short8 pf1 = *(const short8*)(pbase + (16 + l15) * 128
                                          + ((ks * 64 + lg * 16) ^ kswz));
            #pragma unroll
            for (int n = 0; n < 8; ++n) {
                short8 vfn = *(const short8*)((char*)Vt + (n * 16 + l15) * 128
                                              + ((ks * 64 + lg * 16) ^ kswz));
                oacc[0][n] = MFMA16(pf0, vfn, oacc[0][n], 0, 0, 0);
                oacc[1][n] = MFMA16(pf1, vfn, oacc[1][n], 0, 0, 0);
            }
        }
    }

    // ---- epilogue ----
    #pragma unroll
    for (int mt = 0; mt < 2; ++mt) {
        #pragma unroll
        for (int r = 0; r < 4; ++r) {
            const float inv = 1.0f / lrun[mt][r];
            const int qi = q0 + mt * 16 + lg * 4 + r;
            float* orow = outg + ((size_t)(qstart + qi) * HQN + hq) * HD + l15;
            #pragma unroll
            for (int n = 0; n < 8; ++n)
                orow[n * 16] = oacc[mt][n][r] * inv;
        }
    }
}

extern "C" void kernel_launch(void* const* d_in, const int* in_sizes, int n_in,
                              void* d_out, int out_size, void* d_ws, size_t ws_size,
                              hipStream_t stream) {
    const float* q  = (const float*)d_in[0];
    const float* k  = (const float*)d_in[1];
    const float* v  = (const float*)d_in[2];
    const int* btp  = (const int*)d_in[3];
    const int* sl   = (const int*)d_in[4];
    const int* qs   = (const int*)d_in[5];
    float* out      = (float*)d_out;

    attn_fwd<<<dim3(NSEQ * HKVN * 8), 256, 0, stream>>>(q, k, v, btp, sl, qs, out);
}

// Round 6
// 146.386 us; speedup vs baseline: 2.8906x; 1.5310x over previous
//
#include <hip/hip_runtime.h>
#include <stdint.h>

typedef __attribute__((ext_vector_type(8))) short short8;
typedef __attribute__((ext_vector_type(4))) float floatx4;
typedef __attribute__((ext_vector_type(4))) unsigned int uint4v;

#define NSEQ 8
#define BLKSZ 16
#define NBLK_PER_SEQ 128
#define HQN 32
#define HKVN 8
#define GQ 4
#define HD 128
#define WINDOW 1024
#define SCALE 0.08838834764831845f

#define QB 16       // q rows per block (4 waves = 4 GQA heads share K/V)
#define KVB 64      // kv tile
#define KROW 136    // K lds row stride (bf16)
#define VROW 72     // V^T lds row stride
#define PROW 72     // P lds row stride

#define MFMA16 __builtin_amdgcn_mfma_f32_16x16x32_bf16

// two f32 -> packed bf16x2 (round-half-up) via one v_perm
static __device__ __forceinline__ unsigned int pack2bf(float lo, float hi) {
    unsigned int a = __builtin_bit_cast(unsigned int, lo) + 0x8000u;
    unsigned int b = __builtin_bit_cast(unsigned int, hi) + 0x8000u;
    return __builtin_amdgcn_perm(b, a, 0x07060302u);  // low16 = lo>>16, high16 = hi>>16
}
static __device__ __forceinline__ short f2bf(float x) {
    return (short)((__builtin_bit_cast(unsigned int, x) + 0x8000u) >> 16);
}

__global__ __launch_bounds__(256, 2)
void attn_fwd(const float* __restrict__ qg,
              const float* __restrict__ kg,
              const float* __restrict__ vg,
              const int* __restrict__ bt,
              const int* __restrict__ seqlens,
              const int* __restrict__ qsl,
              float* __restrict__ outg)
{
    __shared__ __align__(16) short Klds[KVB][KROW];   // 17408 B
    __shared__ __align__(16) short Vt[HD][VROW];      // 18432 B
    __shared__ __align__(16) short Plds[4][QB][PROW]; //  9216 B  -> 45056 total, 3 blk/CU

    const int tid  = threadIdx.x;
    const int wave = tid >> 6;
    const int lane = tid & 63;
    const int l15  = lane & 15;
    const int lg   = lane >> 4;

    // XCD pinning: consecutive block ids round-robin XCDs -> b&7 = kv head
    const int b  = blockIdx.x;
    const int h  = b & 7;
    const int qt = (b >> 3) & 15;
    const int s  = b >> 7;
    const int q0 = qt * QB;

    const int qstart = qsl[s];
    const int numq   = qsl[s + 1] - qstart;
    const int slen   = seqlens[s];
    const int ctx    = slen - numq;
    const int hq     = h * GQ + wave;

    // ---- Q fragments (A-operand, row = l15), pre-scaled by SCALE ----
    short8 qf[4];
    {
        const float* qrow = qg + ((size_t)(qstart + q0 + l15) * HQN + hq) * HD;
        #pragma unroll
        for (int kt = 0; kt < 4; ++kt) {
            floatx4 f0 = *(const floatx4*)(qrow + kt * 32 + lg * 8);
            floatx4 f1 = *(const floatx4*)(qrow + kt * 32 + lg * 8 + 4);
            uint4v w;
            w[0] = pack2bf(f0[0] * SCALE, f0[1] * SCALE);
            w[1] = pack2bf(f0[2] * SCALE, f0[3] * SCALE);
            w[2] = pack2bf(f1[0] * SCALE, f1[1] * SCALE);
            w[3] = pack2bf(f1[2] * SCALE, f1[3] * SCALE);
            qf[kt] = __builtin_bit_cast(short8, w);
        }
    }

    floatx4 oacc[8];
    #pragma unroll
    for (int n = 0; n < 8; ++n)
        oacc[n] = (floatx4){0.f, 0.f, 0.f, 0.f};

    float mrun[4], lrun[4];
    #pragma unroll
    for (int r = 0; r < 4; ++r) { mrun[r] = -INFINITY; lrun[r] = 0.f; }

    int lo = ctx + q0 - WINDOW + 1; if (lo < 0) lo = 0;
    int hi = ctx + q0 + QB - 1;     if (hi > slen - 1) hi = slen - 1;
    const int t0 = lo / KVB, t1 = hi / KVB;

    // staging maps
    const int srow = tid >> 3;          // K: kv row 0..31 (+32 for p=1)
    const int sd0  = (tid & 7) * 16;    // K: d offset (floats)
    const int k2   = tid & 31;          // V: kv pair index (rows 2k2, 2k2+1)
    const int d0v  = (tid >> 5) * 16;   // V: d offset

    floatx4 fk[8], fv[8];               // raw f32 for next tile (T14 async split)

    // prologue: load tile t0
    {
        const int kv0 = t0 * KVB;
        #pragma unroll
        for (int p = 0; p < 2; ++p) {
            const int kvp = kv0 + p * 32 + srow;
            const int blk = bt[s * NBLK_PER_SEQ + (kvp >> 4)];
            const float* src = kg + (((size_t)blk * BLKSZ + (kvp & 15)) * HKVN + h) * HD + sd0;
            fk[p*4+0] = *(const floatx4*)(src);
            fk[p*4+1] = *(const floatx4*)(src + 4);
            fk[p*4+2] = *(const floatx4*)(src + 8);
            fk[p*4+3] = *(const floatx4*)(src + 12);
        }
        const int kvv = kv0 + 2 * k2;
        const int blk = bt[s * NBLK_PER_SEQ + (kvv >> 4)];
        const float* src = vg + (((size_t)blk * BLKSZ + (kvv & 15)) * HKVN + h) * HD + d0v;
        #pragma unroll
        for (int j = 0; j < 4; ++j) {
            fv[j]     = *(const floatx4*)(src + j * 4);
            fv[4 + j] = *(const floatx4*)(src + (size_t)HKVN * HD + j * 4);
        }
    }

    for (int t = t0; t <= t1; ++t) {
        const int kv0 = t * KVB;
        __syncthreads();   // all waves done with previous tile's LDS

        // ---- convert + store tile t (K row-major, V^T with kv-paired b32) ----
        #pragma unroll
        for (int p = 0; p < 2; ++p) {
            const int row = p * 32 + srow;
            uint4v w;
            w[0] = pack2bf(fk[p*4+0][0], fk[p*4+0][1]);
            w[1] = pack2bf(fk[p*4+0][2], fk[p*4+0][3]);
            w[2] = pack2bf(fk[p*4+1][0], fk[p*4+1][1]);
            w[3] = pack2bf(fk[p*4+1][2], fk[p*4+1][3]);
            *(uint4v*)&Klds[row][sd0] = w;
            w[0] = pack2bf(fk[p*4+2][0], fk[p*4+2][1]);
            w[1] = pack2bf(fk[p*4+2][2], fk[p*4+2][3]);
            w[2] = pack2bf(fk[p*4+3][0], fk[p*4+3][1]);
            w[3] = pack2bf(fk[p*4+3][2], fk[p*4+3][3]);
            *(uint4v*)&Klds[row][sd0 + 8] = w;
        }
        #pragma unroll
        for (int i = 0; i < 16; ++i) {
            // low short = even kv, high = odd kv
            *(unsigned int*)&Vt[d0v + i][2 * k2] =
                pack2bf(fv[i >> 2][i & 3], fv[4 + (i >> 2)][i & 3]);
        }
        __syncthreads();

        // ---- QK^T: S[q][kv] ----
        floatx4 sacc[4];
        #pragma unroll
        for (int nt = 0; nt < 4; ++nt)
            sacc[nt] = (floatx4){0.f, 0.f, 0.f, 0.f};
        #pragma unroll
        for (int kt = 0; kt < 4; ++kt) {
            #pragma unroll
            for (int nt = 0; nt < 4; ++nt) {
                short8 kf = *(const short8*)&Klds[nt * 16 + l15][kt * 32 + lg * 8];
                sacc[nt] = MFMA16(qf[kt], kf, sacc[nt], 0, 0, 0);
            }
        }

        // ---- issue next tile's global loads (overlap with softmax+PV) ----
        if (t < t1) {
            const int kv0n = kv0 + KVB;
            #pragma unroll
            for (int p = 0; p < 2; ++p) {
                const int kvp = kv0n + p * 32 + srow;
                const int blk = bt[s * NBLK_PER_SEQ + (kvp >> 4)];
                const float* src = kg + (((size_t)blk * BLKSZ + (kvp & 15)) * HKVN + h) * HD + sd0;
                fk[p*4+0] = *(const floatx4*)(src);
                fk[p*4+1] = *(const floatx4*)(src + 4);
                fk[p*4+2] = *(const floatx4*)(src + 8);
                fk[p*4+3] = *(const floatx4*)(src + 12);
            }
            const int kvv = kv0n + 2 * k2;
            const int blk = bt[s * NBLK_PER_SEQ + (kvv >> 4)];
            const float* src = vg + (((size_t)blk * BLKSZ + (kvv & 15)) * HKVN + h) * HD + d0v;
            #pragma unroll
            for (int j = 0; j < 4; ++j) {
                fv[j]     = *(const floatx4*)(src + j * 4);
                fv[4 + j] = *(const floatx4*)(src + (size_t)HKVN * HD + j * 4);
            }
        }

        // ---- online softmax (per q-row), interior fast path + defer-max ----
        const bool interior = (kv0 >= ctx + q0 - (WINDOW - QB)) &&
                              (kv0 + KVB - 1 <= ctx + q0);
        #pragma unroll
        for (int r = 0; r < 4; ++r) {
            float sv[4];
            if (interior) {
                #pragma unroll
                for (int nt = 0; nt < 4; ++nt) sv[nt] = sacc[nt][r];
            } else {
                const int qpos = ctx + q0 + lg * 4 + r;
                #pragma unroll
                for (int nt = 0; nt < 4; ++nt) {
                    const int kpos = kv0 + nt * 16 + l15;
                    const bool valid = (kpos <= qpos) && (qpos - kpos < WINDOW);
                    sv[nt] = valid ? sacc[nt][r] : -INFINITY;
                }
            }
            float rmax = fmaxf(fmaxf(sv[0], sv[1]), fmaxf(sv[2], sv[3]));
            rmax = fmaxf(rmax, __shfl_xor(rmax, 1));
            rmax = fmaxf(rmax, __shfl_xor(rmax, 2));
            rmax = fmaxf(rmax, __shfl_xor(rmax, 4));
            rmax = fmaxf(rmax, __shfl_xor(rmax, 8));
            const float mold = mrun[r];
            const bool defer = __all(rmax <= mold + 8.0f);
            const float mnew = defer ? mold : fmaxf(mold, rmax);
            const float alpha = defer ? 1.0f
                : ((mnew == -INFINITY) ? 1.0f : __expf(mold - mnew));
            const bool dead = (mnew == -INFINITY);
            float e[4], rsum = 0.f;
            #pragma unroll
            for (int nt = 0; nt < 4; ++nt) {
                e[nt] = dead ? 0.f : __expf(sv[nt] - mnew);
                rsum += e[nt];
            }
            rsum += __shfl_xor(rsum, 1);
            rsum += __shfl_xor(rsum, 2);
            rsum += __shfl_xor(rsum, 4);
            rsum += __shfl_xor(rsum, 8);
            lrun[r] = lrun[r] * alpha + rsum;
            mrun[r] = mnew;
            if (alpha != 1.0f) {
                #pragma unroll
                for (int n = 0; n < 8; ++n) oacc[n][r] *= alpha;
            }
            const int prow = lg * 4 + r;
            #pragma unroll
            for (int nt = 0; nt < 4; ++nt)
                Plds[wave][prow][nt * 16 + l15] = f2bf(e[nt]);
        }

        // ---- PV: O += P @ V ----
        #pragma unroll
        for (int ks = 0; ks < 2; ++ks) {
            short8 pf = *(const short8*)&Plds[wave][l15][ks * 32 + lg * 8];
            #pragma unroll
            for (int n = 0; n < 8; ++n) {
                short8 vfn = *(const short8*)&Vt[n * 16 + l15][ks * 32 + lg * 8];
                oacc[n] = MFMA16(pf, vfn, oacc[n], 0, 0, 0);
            }
        }
    }

    // ---- epilogue ----
    #pragma unroll
    for (int r = 0; r < 4; ++r) {
        const float inv = 1.0f / lrun[r];
        const int qi = q0 + lg * 4 + r;
        float* orow = outg + ((size_t)(qstart + qi) * HQN + hq) * HD + l15;
        #pragma unroll
        for (int n = 0; n < 8; ++n)
            orow[n * 16] = oacc[n][r] * inv;
    }
}

extern "C" void kernel_launch(void* const* d_in, const int* in_sizes, int n_in,
                              void* d_out, int out_size, void* d_ws, size_t ws_size,
                              hipStream_t stream) {
    const float* q  = (const float*)d_in[0];
    const float* k  = (const float*)d_in[1];
    const float* v  = (const float*)d_in[2];
    const int* btp  = (const int*)d_in[3];
    const int* sl   = (const int*)d_in[4];
    const int* qs   = (const int*)d_in[5];
    float* out      = (float*)d_out;

    attn_fwd<<<dim3(NSEQ * HKVN * (256 / QB)), 256, 0, stream>>>(q, k, v, btp, sl, qs, out);
}

// Round 7
// 96.988 us; speedup vs baseline: 4.3628x; 1.5093x over previous
//
#include <hip/hip_runtime.h>
#include <stdint.h>

typedef __attribute__((ext_vector_type(8))) short short8;
typedef __attribute__((ext_vector_type(4))) float floatx4;
typedef __attribute__((ext_vector_type(4))) unsigned int uint4v;

#define NSEQ 8
#define BLKSZ 16
#define NBLK_PER_SEQ 128
#define HQN 32
#define HKVN 8
#define GQ 4
#define HD 128
#define WINDOW 1024
#define SCALE 0.08838834764831845f

#define QB 32       // q rows per block (4 waves = 4 GQA heads share K/V)
#define KVB 64      // kv tile
#define KROW 136    // K lds row stride (bf16)
#define VROW 72     // V^T lds row stride

#define MFMA16 __builtin_amdgcn_mfma_f32_16x16x32_bf16

// two f32 -> packed bf16x2 (round-half-up) via one v_perm; low16 = lo, high16 = hi
static __device__ __forceinline__ unsigned int pack2bf(float lo, float hi) {
    unsigned int a = __builtin_bit_cast(unsigned int, lo) + 0x8000u;
    unsigned int b = __builtin_bit_cast(unsigned int, hi) + 0x8000u;
    return __builtin_amdgcn_perm(b, a, 0x07060302u);
}

__global__ __launch_bounds__(256, 2)
void attn_fwd(const float* __restrict__ qg,
              const float* __restrict__ kg,
              const float* __restrict__ vg,
              const int* __restrict__ bt,
              const int* __restrict__ seqlens,
              const int* __restrict__ qsl,
              float* __restrict__ outg)
{
    __shared__ __align__(16) short Klds[KVB][KROW];   // 17408 B
    __shared__ __align__(16) short Vt[HD][VROW];      // 18432 B -> 35840 total

    const int tid  = threadIdx.x;
    const int wave = tid >> 6;
    const int lane = tid & 63;
    const int l15  = lane & 15;
    const int lg   = lane >> 4;

    // XCD pinning: consecutive block ids round-robin XCDs -> b&7 = kv head
    const int b  = blockIdx.x;
    const int h  = b & 7;
    const int qt = (b >> 3) & 7;
    const int s  = b >> 6;
    const int q0 = qt * QB;

    const int qstart = qsl[s];
    const int numq   = qsl[s + 1] - qstart;
    const int slen   = seqlens[s];
    const int ctx    = slen - numq;
    const int hq     = h * GQ + wave;

    // ---- Q fragments (B-operand for swapped QK^T: col=l15=q, k=lg*8+j), pre-scaled ----
    short8 qf[2][4];
    #pragma unroll
    for (int nq = 0; nq < 2; ++nq) {
        const float* qrow = qg + ((size_t)(qstart + q0 + nq * 16 + l15) * HQN + hq) * HD;
        #pragma unroll
        for (int kt = 0; kt < 4; ++kt) {
            floatx4 f0 = *(const floatx4*)(qrow + kt * 32 + lg * 8);
            floatx4 f1 = *(const floatx4*)(qrow + kt * 32 + lg * 8 + 4);
            uint4v w;
            w[0] = pack2bf(f0[0] * SCALE, f0[1] * SCALE);
            w[1] = pack2bf(f0[2] * SCALE, f0[3] * SCALE);
            w[2] = pack2bf(f1[0] * SCALE, f1[1] * SCALE);
            w[3] = pack2bf(f1[2] * SCALE, f1[3] * SCALE);
            qf[nq][kt] = __builtin_bit_cast(short8, w);
        }
    }

    // O^T accumulators: oacc[nq][dt]; lane: d = dt*16 + lg*4 + r, q = nq*16 + l15
    floatx4 oacc[2][8];
    #pragma unroll
    for (int nq = 0; nq < 2; ++nq)
        #pragma unroll
        for (int dt = 0; dt < 8; ++dt)
            oacc[nq][dt] = (floatx4){0.f, 0.f, 0.f, 0.f};

    // per-lane online-softmax state for q = nq*16 + l15
    float mrun[2] = {-INFINITY, -INFINITY};
    float lrun[2] = {0.f, 0.f};

    int lo = ctx + q0 - WINDOW + 1; if (lo < 0) lo = 0;
    int hi = ctx + q0 + QB - 1;     if (hi > slen - 1) hi = slen - 1;
    const int t0 = lo / KVB, t1 = hi / KVB;

    // staging maps (verbatim R2)
    const int srow = tid >> 3;          // K: kv row 0..31 (+32 for p=1)
    const int sd0  = (tid & 7) * 16;    // K: d offset (floats)
    const int k2   = tid & 31;          // V: kv pair index (rows 2k2, 2k2+1)
    const int d0v  = (tid >> 5) * 16;   // V: d offset

    floatx4 fk[8], fv[8];               // raw f32 for next tile (T14 async split)

    // prologue: load tile t0
    {
        const int kv0 = t0 * KVB;
        #pragma unroll
        for (int p = 0; p < 2; ++p) {
            const int kvp = kv0 + p * 32 + srow;
            const int blk = bt[s * NBLK_PER_SEQ + (kvp >> 4)];
            const float* src = kg + (((size_t)blk * BLKSZ + (kvp & 15)) * HKVN + h) * HD + sd0;
            fk[p*4+0] = *(const floatx4*)(src);
            fk[p*4+1] = *(const floatx4*)(src + 4);
            fk[p*4+2] = *(const floatx4*)(src + 8);
            fk[p*4+3] = *(const floatx4*)(src + 12);
        }
        const int kvv = kv0 + 2 * k2;
        const int blk = bt[s * NBLK_PER_SEQ + (kvv >> 4)];
        const float* src = vg + (((size_t)blk * BLKSZ + (kvv & 15)) * HKVN + h) * HD + d0v;
        #pragma unroll
        for (int j = 0; j < 4; ++j) {
            fv[j]     = *(const floatx4*)(src + j * 4);
            fv[4 + j] = *(const floatx4*)(src + (size_t)HKVN * HD + j * 4);
        }
    }

    for (int t = t0; t <= t1; ++t) {
        const int kv0 = t * KVB;
        __syncthreads();   // all waves done with previous tile's LDS

        // ---- convert + store tile t (K row-major, V^T kv-paired b32) — verbatim R2 ----
        #pragma unroll
        for (int p = 0; p < 2; ++p) {
            const int row = p * 32 + srow;
            uint4v w;
            w[0] = pack2bf(fk[p*4+0][0], fk[p*4+0][1]);
            w[1] = pack2bf(fk[p*4+0][2], fk[p*4+0][3]);
            w[2] = pack2bf(fk[p*4+1][0], fk[p*4+1][1]);
            w[3] = pack2bf(fk[p*4+1][2], fk[p*4+1][3]);
            *(uint4v*)&Klds[row][sd0] = w;
            w[0] = pack2bf(fk[p*4+2][0], fk[p*4+2][1]);
            w[1] = pack2bf(fk[p*4+2][2], fk[p*4+2][3]);
            w[2] = pack2bf(fk[p*4+3][0], fk[p*4+3][1]);
            w[3] = pack2bf(fk[p*4+3][2], fk[p*4+3][3]);
            *(uint4v*)&Klds[row][sd0 + 8] = w;
        }
        #pragma unroll
        for (int i = 0; i < 16; ++i) {
            *(unsigned int*)&Vt[d0v + i][2 * k2] =
                pack2bf(fv[i >> 2][i & 3], fv[4 + (i >> 2)][i & 3]);
        }
        __syncthreads();

        // ---- swapped QK^T: S^T[kv][q] = mfma(A=K, B=Q) ----
        // sacc[nq][m2]: kv = kv0 + m2*16 + lg*4 + r, q = q0 + nq*16 + l15
        floatx4 sacc[2][4];
        #pragma unroll
        for (int nq = 0; nq < 2; ++nq)
            #pragma unroll
            for (int m2 = 0; m2 < 4; ++m2)
                sacc[nq][m2] = (floatx4){0.f, 0.f, 0.f, 0.f};
        #pragma unroll
        for (int kt = 0; kt < 4; ++kt) {
            #pragma unroll
            for (int m2 = 0; m2 < 4; ++m2) {
                short8 kf = *(const short8*)&Klds[m2 * 16 + l15][kt * 32 + lg * 8];
                sacc[0][m2] = MFMA16(kf, qf[0][kt], sacc[0][m2], 0, 0, 0);
                sacc[1][m2] = MFMA16(kf, qf[1][kt], sacc[1][m2], 0, 0, 0);
            }
        }

        // ---- issue next tile's global loads (overlap with softmax+PV) ----
        if (t < t1) {
            const int kv0n = kv0 + KVB;
            #pragma unroll
            for (int p = 0; p < 2; ++p) {
                const int kvp = kv0n + p * 32 + srow;
                const int blk = bt[s * NBLK_PER_SEQ + (kvp >> 4)];
                const float* src = kg + (((size_t)blk * BLKSZ + (kvp & 15)) * HKVN + h) * HD + sd0;
                fk[p*4+0] = *(const floatx4*)(src);
                fk[p*4+1] = *(const floatx4*)(src + 4);
                fk[p*4+2] = *(const floatx4*)(src + 8);
                fk[p*4+3] = *(const floatx4*)(src + 12);
            }
            const int kvv = kv0n + 2 * k2;
            const int blk = bt[s * NBLK_PER_SEQ + (kvv >> 4)];
            const float* src = vg + (((size_t)blk * BLKSZ + (kvv & 15)) * HKVN + h) * HD + d0v;
            #pragma unroll
            for (int j = 0; j < 4; ++j) {
                fv[j]     = *(const floatx4*)(src + j * 4);
                fv[4 + j] = *(const floatx4*)(src + (size_t)HKVN * HD + j * 4);
            }
        }

        // ---- in-register online softmax (q = l15 lane-local) + P^T exchange ----
        const bool interior = (kv0 >= ctx + q0 - (WINDOW - QB)) &&
                              (kv0 + KVB - 1 <= ctx + q0);
        short8 pfv[2][2];   // [ks][nq] B-frag of P^T
        const int srcA = ((lg & 1) << 5) + l15;
        const int srcB = srcA + 16;
        const bool hiSel = (lg >> 1) != 0;
        #pragma unroll
        for (int nq = 0; nq < 2; ++nq) {
            const int qpos = ctx + q0 + nq * 16 + l15;
            float sv[4][4];
            #pragma unroll
            for (int m2 = 0; m2 < 4; ++m2) {
                #pragma unroll
                for (int r = 0; r < 4; ++r) {
                    float x = sacc[nq][m2][r];
                    if (!interior) {
                        const int kpos = kv0 + m2 * 16 + lg * 4 + r;
                        const bool valid = (kpos <= qpos) && (qpos - kpos < WINDOW);
                        x = valid ? x : -INFINITY;
                    }
                    sv[m2][r] = x;
                }
            }
            // row max: 15 in-reg + 2 shfl (across lg groups)
            float rmax = -INFINITY;
            #pragma unroll
            for (int m2 = 0; m2 < 4; ++m2)
                #pragma unroll
                for (int r = 0; r < 4; ++r)
                    rmax = fmaxf(rmax, sv[m2][r]);
            rmax = fmaxf(rmax, __shfl_xor(rmax, 16));
            rmax = fmaxf(rmax, __shfl_xor(rmax, 32));
            const float mold = mrun[nq];
            const bool defer = __all(rmax <= mold + 8.0f);
            const float mnew = defer ? mold : fmaxf(mold, rmax);
            const float alpha = defer ? 1.0f
                : ((mold == -INFINITY) ? ((mnew == -INFINITY) ? 1.0f : 0.0f)
                                       : __expf(mold - mnew));
            const bool dead = (mnew == -INFINITY);
            float rsum = 0.f;
            #pragma unroll
            for (int m2 = 0; m2 < 4; ++m2)
                #pragma unroll
                for (int r = 0; r < 4; ++r) {
                    float e = dead ? 0.f : __expf(sv[m2][r] - mnew);
                    sv[m2][r] = e;
                    rsum += e;
                }
            rsum += __shfl_xor(rsum, 16);
            rsum += __shfl_xor(rsum, 32);
            lrun[nq] = lrun[nq] * alpha + rsum;
            mrun[nq] = mnew;
            if (!defer) {
                #pragma unroll
                for (int dt = 0; dt < 8; ++dt) {
                    oacc[nq][dt][0] *= alpha; oacc[nq][dt][1] *= alpha;
                    oacc[nq][dt][2] *= alpha; oacc[nq][dt][3] *= alpha;
                }
            }
            // pack P^T: pk0[m2]=(r0,r1), pk1[m2]=(r2,r3)
            unsigned int pk0[4], pk1[4];
            #pragma unroll
            for (int m2 = 0; m2 < 4; ++m2) {
                pk0[m2] = pack2bf(sv[m2][0], sv[m2][1]);
                pk1[m2] = pack2bf(sv[m2][2], sv[m2][3]);
            }
            // exchange to B-frag: lane (lg,l15) word t holds P^T[kv=ks*32+lg*8+2t(,+1)][q]
            // m2sel = 2ks + (lg>>1); srcA gives j0..3 (lg'=(lg&1)*2), srcB gives j4..7
            #pragma unroll
            for (int ks = 0; ks < 2; ++ks) {
                unsigned int a0 = (unsigned int)__shfl((int)pk0[2*ks],   srcA, 64);
                unsigned int a1 = (unsigned int)__shfl((int)pk0[2*ks+1], srcA, 64);
                unsigned int b0 = (unsigned int)__shfl((int)pk1[2*ks],   srcA, 64);
                unsigned int b1 = (unsigned int)__shfl((int)pk1[2*ks+1], srcA, 64);
                unsigned int c0 = (unsigned int)__shfl((int)pk0[2*ks],   srcB, 64);
                unsigned int c1 = (unsigned int)__shfl((int)pk0[2*ks+1], srcB, 64);
                unsigned int d0 = (unsigned int)__shfl((int)pk1[2*ks],   srcB, 64);
                unsigned int d1 = (unsigned int)__shfl((int)pk1[2*ks+1], srcB, 64);
                uint4v w;
                w[0] = hiSel ? a1 : a0;
                w[1] = hiSel ? b1 : b0;
                w[2] = hiSel ? c1 : c0;
                w[3] = hiSel ? d1 : d0;
                pfv[ks][nq] = __builtin_bit_cast(short8, w);
            }
        }

        // ---- PV swapped: O^T += mfma(A=V^T, B=P^T) ----
        #pragma unroll
        for (int ks = 0; ks < 2; ++ks) {
            #pragma unroll
            for (int dt = 0; dt < 8; ++dt) {
                short8 vfn = *(const short8*)&Vt[dt * 16 + l15][ks * 32 + lg * 8];
                oacc[0][dt] = MFMA16(vfn, pfv[ks][0], oacc[0][dt], 0, 0, 0);
                oacc[1][dt] = MFMA16(vfn, pfv[ks][1], oacc[1][dt], 0, 0, 0);
            }
        }
    }

    // ---- epilogue: lane-local normalize, b128 stores ----
    #pragma unroll
    for (int nq = 0; nq < 2; ++nq) {
        const float inv = 1.0f / lrun[nq];
        float* orow = outg + ((size_t)(qstart + q0 + nq * 16 + l15) * HQN + hq) * HD + lg * 4;
        #pragma unroll
        for (int dt = 0; dt < 8; ++dt) {
            floatx4 o = oacc[nq][dt];
            o[0] *= inv; o[1] *= inv; o[2] *= inv; o[3] *= inv;
            *(floatx4*)(orow + dt * 16) = o;
        }
    }
}

extern "C" void kernel_launch(void* const* d_in, const int* in_sizes, int n_in,
                              void* d_out, int out_size, void* d_ws, size_t ws_size,
                              hipStream_t stream) {
    const float* q  = (const float*)d_in[0];
    const float* k  = (const float*)d_in[1];
    const float* v  = (const float*)d_in[2];
    const int* btp  = (const int*)d_in[3];
    const int* sl   = (const int*)d_in[4];
    const int* qs   = (const int*)d_in[5];
    float* out      = (float*)d_out;

    attn_fwd<<<dim3(NSEQ * HKVN * 8), 256, 0, stream>>>(q, k, v, btp, sl, qs, out);
}

// Round 8
// 92.881 us; speedup vs baseline: 4.5558x; 1.0442x over previous
//
#include <hip/hip_runtime.h>
#include <stdint.h>

typedef __attribute__((ext_vector_type(8))) short short8;
typedef __attribute__((ext_vector_type(4))) float floatx4;
typedef __attribute__((ext_vector_type(4))) unsigned int uint4v;

#define NSEQ 8
#define BLKSZ 16
#define NBLK_PER_SEQ 128
#define HQN 32
#define HKVN 8
#define GQ 4
#define HD 128
#define WINDOW 1024
#define SCALE 0.08838834764831845f

#define QB 32       // q rows per block (4 waves = 4 GQA heads share K/V)
#define KVB 32      // kv tile (double-buffered)
#define KROW 136    // K lds row stride (bf16)
#define VROW 40     // V^T lds row stride

#define MFMA16 __builtin_amdgcn_mfma_f32_16x16x32_bf16

// two f32 -> packed bf16x2 (round-half-up) via one v_perm; low16 = lo, high16 = hi
static __device__ __forceinline__ unsigned int pack2bf(float lo, float hi) {
    unsigned int a = __builtin_bit_cast(unsigned int, lo) + 0x8000u;
    unsigned int b = __builtin_bit_cast(unsigned int, hi) + 0x8000u;
    return __builtin_amdgcn_perm(b, a, 0x07060302u);
}

__global__ __launch_bounds__(256, 2)
void attn_fwd(const float* __restrict__ qg,
              const float* __restrict__ kg,
              const float* __restrict__ vg,
              const int* __restrict__ bt,
              const int* __restrict__ seqlens,
              const int* __restrict__ qsl,
              float* __restrict__ outg)
{
    __shared__ __align__(16) short Klds[2][KVB][KROW];  // 2 x 8704 B
    __shared__ __align__(16) short Vt[2][HD][VROW];     // 2 x 10240 B -> 37888 total

    const int tid  = threadIdx.x;
    const int lane = tid & 63;
    const int wave = tid >> 6;
    const int l15  = lane & 15;
    const int lg   = lane >> 4;

    // XCD pinning: consecutive block ids round-robin XCDs -> b&7 = kv head
    const int b  = blockIdx.x;
    const int h  = b & 7;
    const int qt = (b >> 3) & 7;
    const int s  = b >> 6;
    const int q0 = qt * QB;

    const int qstart = qsl[s];
    const int numq   = qsl[s + 1] - qstart;
    const int slen   = seqlens[s];
    const int ctx    = slen - numq;
    const int hq     = h * GQ + wave;

    // ---- Q fragments (B-operand for swapped QK^T: col=l15=q, k=kt*32+lg*8+j), pre-scaled ----
    short8 qf[2][4];
    #pragma unroll
    for (int nq = 0; nq < 2; ++nq) {
        const float* qrow = qg + ((size_t)(qstart + q0 + nq * 16 + l15) * HQN + hq) * HD;
        #pragma unroll
        for (int kt = 0; kt < 4; ++kt) {
            floatx4 f0 = *(const floatx4*)(qrow + kt * 32 + lg * 8);
            floatx4 f1 = *(const floatx4*)(qrow + kt * 32 + lg * 8 + 4);
            uint4v w;
            w[0] = pack2bf(f0[0] * SCALE, f0[1] * SCALE);
            w[1] = pack2bf(f0[2] * SCALE, f0[3] * SCALE);
            w[2] = pack2bf(f1[0] * SCALE, f1[1] * SCALE);
            w[3] = pack2bf(f1[2] * SCALE, f1[3] * SCALE);
            qf[nq][kt] = __builtin_bit_cast(short8, w);
        }
    }

    // O^T accumulators: oacc[nq][dt]; lane: d = dt*16 + lg*4 + r, q = nq*16 + l15
    floatx4 oacc[2][8];
    #pragma unroll
    for (int nq = 0; nq < 2; ++nq)
        #pragma unroll
        for (int dt = 0; dt < 8; ++dt)
            oacc[nq][dt] = (floatx4){0.f, 0.f, 0.f, 0.f};

    float mrun[2] = {-INFINITY, -INFINITY};
    float lrun[2] = {0.f, 0.f};

    int lo = ctx + q0 - WINDOW + 1; if (lo < 0) lo = 0;
    int hi = ctx + q0 + QB - 1;     if (hi > slen - 1) hi = slen - 1;
    const int t0 = lo / KVB, t1 = hi / KVB;

    // staging maps
    const int srow = tid >> 3;          // K: kv row 0..31
    const int sd0  = (tid & 7) * 16;    // K: d offset (floats)
    const int k2   = tid & 15;          // V: kv pair index (rows 2k2, 2k2+1)
    const int d0v  = (tid >> 4) * 8;    // V: d offset (0..120)

    floatx4 fk[4], fv[4];               // raw f32 for next tile (T14 async split)

#define LOAD_TILE(kv0_) {                                                            \
        const int kvp = (kv0_) + srow;                                               \
        const int blk = bt[s * NBLK_PER_SEQ + (kvp >> 4)];                           \
        const float* src = kg + (((size_t)blk * BLKSZ + (kvp & 15)) * HKVN + h) * HD + sd0; \
        fk[0] = *(const floatx4*)(src);                                              \
        fk[1] = *(const floatx4*)(src + 4);                                          \
        fk[2] = *(const floatx4*)(src + 8);                                          \
        fk[3] = *(const floatx4*)(src + 12);                                         \
        const int kvv = (kv0_) + 2 * k2;                                             \
        const int blkv = bt[s * NBLK_PER_SEQ + (kvv >> 4)];                          \
        const float* vsrc = vg + (((size_t)blkv * BLKSZ + (kvv & 15)) * HKVN + h) * HD + d0v; \
        fv[0] = *(const floatx4*)(vsrc);                                             \
        fv[1] = *(const floatx4*)(vsrc + 4);                                         \
        fv[2] = *(const floatx4*)(vsrc + (size_t)HKVN * HD);                         \
        fv[3] = *(const floatx4*)(vsrc + (size_t)HKVN * HD + 4);                     \
    }

    // prologue: load tile t0 into regs
    LOAD_TILE(t0 * KVB);

    int cur = 0;
    for (int t = t0; t <= t1; ++t) {
        const int kv0 = t * KVB;

        // ---- convert + store tile t into buf[cur] (before barrier) ----
        {
            uint4v w;
            w[0] = pack2bf(fk[0][0], fk[0][1]);
            w[1] = pack2bf(fk[0][2], fk[0][3]);
            w[2] = pack2bf(fk[1][0], fk[1][1]);
            w[3] = pack2bf(fk[1][2], fk[1][3]);
            *(uint4v*)&Klds[cur][srow][sd0] = w;
            w[0] = pack2bf(fk[2][0], fk[2][1]);
            w[1] = pack2bf(fk[2][2], fk[2][3]);
            w[2] = pack2bf(fk[3][0], fk[3][1]);
            w[3] = pack2bf(fk[3][2], fk[3][3]);
            *(uint4v*)&Klds[cur][srow][sd0 + 8] = w;
            #pragma unroll
            for (int i = 0; i < 8; ++i) {
                // low short = even kv, high = odd kv
                *(unsigned int*)&Vt[cur][d0v + i][2 * k2] =
                    pack2bf(fv[i >> 2][i & 3], fv[2 + (i >> 2)][i & 3]);
            }
        }

        // ---- issue next tile's global loads (hide under barrier + compute) ----
        if (t < t1) LOAD_TILE(kv0 + KVB);

        __syncthreads();   // buf[cur] visible; prev readers of buf[cur^1] long done

        // ---- swapped QK^T: S^T[kv][q] = mfma(A=K, B=Q) ----
        // sacc[nq][m2]: kv = kv0 + m2*16 + lg*4 + r, q = q0 + nq*16 + l15
        floatx4 sacc[2][2];
        sacc[0][0] = (floatx4){0.f,0.f,0.f,0.f}; sacc[0][1] = (floatx4){0.f,0.f,0.f,0.f};
        sacc[1][0] = (floatx4){0.f,0.f,0.f,0.f}; sacc[1][1] = (floatx4){0.f,0.f,0.f,0.f};
        #pragma unroll
        for (int kt = 0; kt < 4; ++kt) {
            #pragma unroll
            for (int m2 = 0; m2 < 2; ++m2) {
                short8 kf = *(const short8*)&Klds[cur][m2 * 16 + l15][kt * 32 + lg * 8];
                sacc[0][m2] = MFMA16(kf, qf[0][kt], sacc[0][m2], 0, 0, 0);
                sacc[1][m2] = MFMA16(kf, qf[1][kt], sacc[1][m2], 0, 0, 0);
            }
        }

        // ---- in-register online softmax (q = l15 lane-local) + P^T exchange ----
        const bool interior = (kv0 >= ctx + q0 - (WINDOW - QB)) &&
                              (kv0 + KVB - 1 <= ctx + q0);
        short8 pfv[2];   // [nq] B-frag of P^T
        const int srcA = ((lg & 1) << 5) + l15;
        const int srcB = srcA + 16;
        const bool hiSel = (lg >> 1) != 0;
        #pragma unroll
        for (int nq = 0; nq < 2; ++nq) {
            const int qpos = ctx + q0 + nq * 16 + l15;
            float sv[2][4];
            #pragma unroll
            for (int m2 = 0; m2 < 2; ++m2) {
                #pragma unroll
                for (int r = 0; r < 4; ++r) {
                    float x = sacc[nq][m2][r];
                    if (!interior) {
                        const int kpos = kv0 + m2 * 16 + lg * 4 + r;
                        const bool valid = (kpos <= qpos) && (qpos - kpos < WINDOW);
                        x = valid ? x : -INFINITY;
                    }
                    sv[m2][r] = x;
                }
            }
            float rmax = -INFINITY;
            #pragma unroll
            for (int m2 = 0; m2 < 2; ++m2)
                #pragma unroll
                for (int r = 0; r < 4; ++r)
                    rmax = fmaxf(rmax, sv[m2][r]);
            rmax = fmaxf(rmax, __shfl_xor(rmax, 16));
            rmax = fmaxf(rmax, __shfl_xor(rmax, 32));
            const float mold = mrun[nq];
            const bool defer = __all(rmax <= mold + 8.0f);
            const float mnew = defer ? mold : fmaxf(mold, rmax);
            const float alpha = defer ? 1.0f
                : ((mold == -INFINITY) ? ((mnew == -INFINITY) ? 1.0f : 0.0f)
                                       : __expf(mold - mnew));
            const bool dead = (mnew == -INFINITY);
            float rsum = 0.f;
            #pragma unroll
            for (int m2 = 0; m2 < 2; ++m2)
                #pragma unroll
                for (int r = 0; r < 4; ++r) {
                    float e = dead ? 0.f : __expf(sv[m2][r] - mnew);
                    sv[m2][r] = e;
                    rsum += e;
                }
            rsum += __shfl_xor(rsum, 16);
            rsum += __shfl_xor(rsum, 32);
            lrun[nq] = lrun[nq] * alpha + rsum;
            mrun[nq] = mnew;
            if (!defer) {
                #pragma unroll
                for (int dt = 0; dt < 8; ++dt) {
                    oacc[nq][dt][0] *= alpha; oacc[nq][dt][1] *= alpha;
                    oacc[nq][dt][2] *= alpha; oacc[nq][dt][3] *= alpha;
                }
            }
            // pack P^T: pk0[m2]=(r0,r1), pk1[m2]=(r2,r3)
            unsigned int pk0[2], pk1[2];
            #pragma unroll
            for (int m2 = 0; m2 < 2; ++m2) {
                pk0[m2] = pack2bf(sv[m2][0], sv[m2][1]);
                pk1[m2] = pack2bf(sv[m2][2], sv[m2][3]);
            }
            // exchange to B-frag: lane (lg,l15) word t = P^T[kv=lg*8+2t(,+1)][q=l15]
            {
                unsigned int a0 = (unsigned int)__shfl((int)pk0[0], srcA, 64);
                unsigned int a1 = (unsigned int)__shfl((int)pk0[1], srcA, 64);
                unsigned int b0 = (unsigned int)__shfl((int)pk1[0], srcA, 64);
                unsigned int b1 = (unsigned int)__shfl((int)pk1[1], srcA, 64);
                unsigned int c0 = (unsigned int)__shfl((int)pk0[0], srcB, 64);
                unsigned int c1 = (unsigned int)__shfl((int)pk0[1], srcB, 64);
                unsigned int d0 = (unsigned int)__shfl((int)pk1[0], srcB, 64);
                unsigned int d1 = (unsigned int)__shfl((int)pk1[1], srcB, 64);
                uint4v w;
                w[0] = hiSel ? a1 : a0;
                w[1] = hiSel ? b1 : b0;
                w[2] = hiSel ? c1 : c0;
                w[3] = hiSel ? d1 : d0;
                pfv[nq] = __builtin_bit_cast(short8, w);
            }
        }

        // ---- PV swapped: O^T += mfma(A=V^T, B=P^T) ----
        #pragma unroll
        for (int dt = 0; dt < 8; ++dt) {
            short8 vfn = *(const short8*)&Vt[cur][dt * 16 + l15][lg * 8];
            oacc[0][dt] = MFMA16(vfn, pfv[0], oacc[0][dt], 0, 0, 0);
            oacc[1][dt] = MFMA16(vfn, pfv[1], oacc[1][dt], 0, 0, 0);
        }

        cur ^= 1;
    }
#undef LOAD_TILE

    // ---- epilogue: lane-local normalize, b128 stores ----
    #pragma unroll
    for (int nq = 0; nq < 2; ++nq) {
        const float inv = 1.0f / lrun[nq];
        float* orow = outg + ((size_t)(qstart + q0 + nq * 16 + l15) * HQN + hq) * HD + lg * 4;
        #pragma unroll
        for (int dt = 0; dt < 8; ++dt) {
            floatx4 o = oacc[nq][dt];
            o[0] *= inv; o[1] *= inv; o[2] *= inv; o[3] *= inv;
            *(floatx4*)(orow + dt * 16) = o;
        }
    }
}

extern "C" void kernel_launch(void* const* d_in, const int* in_sizes, int n_in,
                              void* d_out, int out_size, void* d_ws, size_t ws_size,
                              hipStream_t stream) {
    const float* q  = (const float*)d_in[0];
    const float* k  = (const float*)d_in[1];
    const float* v  = (const float*)d_in[2];
    const int* btp  = (const int*)d_in[3];
    const int* sl   = (const int*)d_in[4];
    const int* qs   = (const int*)d_in[5];
    float* out      = (float*)d_out;

    attn_fwd<<<dim3(NSEQ * HKVN * 8), 256, 0, stream>>>(q, k, v, btp, sl, qs, out);
}

// Round 11
// 85.152 us; speedup vs baseline: 4.9693x; 1.0908x over previous
//
#include <hip/hip_runtime.h>
#include <stdint.h>

typedef __attribute__((ext_vector_type(8))) short short8;
typedef __attribute__((ext_vector_type(4))) float floatx4;
typedef __attribute__((ext_vector_type(16))) float f32x16;
typedef __attribute__((ext_vector_type(4))) unsigned int uint4v;

#define NSEQ 8
#define BLKSZ 16
#define NBLK_PER_SEQ 128
#define HQN 32
#define HKVN 8
#define GQ 4
#define HD 128
#define WINDOW 1024
#define SCALE 0.08838834764831845f

#define QB 32       // q rows per block (4 waves = 4 GQA heads share K/V)
#define KVB 32      // kv tile (double-buffered)
#define KROW 136    // K lds row stride (bf16)
#define VROW 40     // V^T lds row stride

#define MFMA32 __builtin_amdgcn_mfma_f32_32x32x16_bf16

// two f32 -> packed bf16x2 (round-half-up) via one v_perm; low16 = lo, high16 = hi
static __device__ __forceinline__ unsigned int pack2bf(float lo, float hi) {
    unsigned int a = __builtin_bit_cast(unsigned int, lo) + 0x8000u;
    unsigned int b = __builtin_bit_cast(unsigned int, hi) + 0x8000u;
    return __builtin_amdgcn_perm(b, a, 0x07060302u);
}

__global__ __launch_bounds__(256, 2)
void attn_fwd(const float* __restrict__ qg,
              const float* __restrict__ kg,
              const float* __restrict__ vg,
              const int* __restrict__ bt,
              const int* __restrict__ seqlens,
              const int* __restrict__ qsl,
              float* __restrict__ outg)
{
    __shared__ __align__(16) short Klds[2][KVB][KROW];  // 2 x 8704 B
    __shared__ __align__(16) short Vt[2][HD][VROW];     // 2 x 10240 B -> 37888 total

    const int tid  = threadIdx.x;
    const int lane = tid & 63;
    const int wave = tid >> 6;
    const int l31  = lane & 31;
    const int hi   = lane >> 5;

    // XCD pinning: consecutive block ids round-robin XCDs -> b&7 = kv head
    const int b  = blockIdx.x;
    const int h  = b & 7;
    const int qt = (b >> 3) & 7;
    const int s  = b >> 6;
    const int q0 = qt * QB;

    const int qstart = qsl[s];
    const int numq   = qsl[s + 1] - qstart;
    const int slen   = seqlens[s];
    const int ctx    = slen - numq;
    const int hq     = h * GQ + wave;

    // ---- Q fragments (B-operand 32x32x16: col=q=l31, k=ks*16+hi*8+j), pre-scaled ----
    short8 qf[8];
    {
        const float* qrow = qg + ((size_t)(qstart + q0 + l31) * HQN + hq) * HD;
        #pragma unroll
        for (int ks = 0; ks < 8; ++ks) {
            floatx4 f0 = *(const floatx4*)(qrow + ks * 16 + hi * 8);
            floatx4 f1 = *(const floatx4*)(qrow + ks * 16 + hi * 8 + 4);
            uint4v w;
            w[0] = pack2bf(f0[0] * SCALE, f0[1] * SCALE);
            w[1] = pack2bf(f0[2] * SCALE, f0[3] * SCALE);
            w[2] = pack2bf(f1[0] * SCALE, f1[1] * SCALE);
            w[3] = pack2bf(f1[2] * SCALE, f1[3] * SCALE);
            qf[ks] = __builtin_bit_cast(short8, w);
        }
    }

    // O^T accumulators: oacc[dblk]; lane: q = l31, d = dblk*32 + (r&3) + 8*(r>>2) + 4*hi
    f32x16 oacc[4];
    #pragma unroll
    for (int dblk = 0; dblk < 4; ++dblk)
        #pragma unroll
        for (int i = 0; i < 16; ++i)
            oacc[dblk][i] = 0.f;

    float mrun = -INFINITY, lrun = 0.f;

    int lo = ctx + q0 - WINDOW + 1; if (lo < 0) lo = 0;
    int hiq = ctx + q0 + QB - 1;    if (hiq > slen - 1) hiq = slen - 1;
    const int t0 = lo / KVB, t1 = hiq / KVB;

    // staging maps (verbatim R8)
    const int srow = tid >> 3;          // K: kv row 0..31
    const int sd0  = (tid & 7) * 16;    // K: d offset (floats)
    const int k2   = tid & 15;          // V: kv pair index (rows 2k2, 2k2+1)
    const int d0v  = (tid >> 4) * 8;    // V: d offset (0..120)

    floatx4 fk[4], fv[4];               // raw f32 for next tile (T14 async split)

#define LOAD_TILE(kv0_) {                                                            \
        const int kvp = (kv0_) + srow;                                               \
        const int blk = bt[s * NBLK_PER_SEQ + (kvp >> 4)];                           \
        const float* src = kg + (((size_t)blk * BLKSZ + (kvp & 15)) * HKVN + h) * HD + sd0; \
        fk[0] = *(const floatx4*)(src);                                              \
        fk[1] = *(const floatx4*)(src + 4);                                          \
        fk[2] = *(const floatx4*)(src + 8);                                          \
        fk[3] = *(const floatx4*)(src + 12);                                         \
        const int kvv = (kv0_) + 2 * k2;                                             \
        const int blkv = bt[s * NBLK_PER_SEQ + (kvv >> 4)];                          \
        const float* vsrc = vg + (((size_t)blkv * BLKSZ + (kvv & 15)) * HKVN + h) * HD + d0v; \
        fv[0] = *(const floatx4*)(vsrc);                                             \
        fv[1] = *(const floatx4*)(vsrc + 4);                                         \
        fv[2] = *(const floatx4*)(vsrc + (size_t)HKVN * HD);                         \
        fv[3] = *(const floatx4*)(vsrc + (size_t)HKVN * HD + 4);                     \
    }

    LOAD_TILE(t0 * KVB);

    int cur = 0;
    for (int t = t0; t <= t1; ++t) {
        const int kv0 = t * KVB;

        // ---- convert + store tile t into buf[cur] (before barrier) ----
        {
            uint4v w;
            w[0] = pack2bf(fk[0][0], fk[0][1]);
            w[1] = pack2bf(fk[0][2], fk[0][3]);
            w[2] = pack2bf(fk[1][0], fk[1][1]);
            w[3] = pack2bf(fk[1][2], fk[1][3]);
            *(uint4v*)&Klds[cur][srow][sd0] = w;
            w[0] = pack2bf(fk[2][0], fk[2][1]);
            w[1] = pack2bf(fk[2][2], fk[2][3]);
            w[2] = pack2bf(fk[3][0], fk[3][1]);
            w[3] = pack2bf(fk[3][2], fk[3][3]);
            *(uint4v*)&Klds[cur][srow][sd0 + 8] = w;
            #pragma unroll
            for (int i = 0; i < 8; ++i) {
                // low short = even kv, high = odd kv
                *(unsigned int*)&Vt[cur][d0v + i][2 * k2] =
                    pack2bf(fv[i >> 2][i & 3], fv[2 + (i >> 2)][i & 3]);
            }
        }

        // ---- issue next tile's global loads (hide under barrier + compute) ----
        if (t < t1) LOAD_TILE(kv0 + KVB);

        __syncthreads();   // buf[cur] visible; prev readers of buf[cur^1] long done

        // ---- swapped QK^T 32x32: S^T[kv][q] = mfma32(A=K, B=Q) ----
        f32x16 sacc;
        #pragma unroll
        for (int i = 0; i < 16; ++i) sacc[i] = 0.f;
        #pragma unroll
        for (int ks = 0; ks < 8; ++ks) {
            short8 kf = *(const short8*)&Klds[cur][l31][ks * 16 + hi * 8];
            sacc = MFMA32(kf, qf[ks], sacc, 0, 0, 0);
        }

        // ---- lane-local online softmax (q = l31) ----
        const bool interior = (kv0 >= ctx + q0 - (WINDOW - QB)) &&
                              (kv0 + KVB - 1 <= ctx + q0);
        const int qpos = ctx + q0 + l31;
        float p[16];
        float rmax = -INFINITY;
        #pragma unroll
        for (int r = 0; r < 16; ++r) {
            float x = sacc[r];
            if (!interior) {
                const int kpos = kv0 + (r & 3) + 4 * hi + 8 * (r >> 2);
                const bool valid = (kpos <= qpos) && (qpos - kpos < WINDOW);
                x = valid ? x : -INFINITY;
            }
            p[r] = x;
            rmax = fmaxf(rmax, x);
        }
        rmax = fmaxf(rmax, __shfl_xor(rmax, 32));
        const float mold = mrun;
        const bool defer = __all(rmax <= mold + 8.0f);
        const float mnew = defer ? mold : fmaxf(mold, rmax);
        const float alpha = defer ? 1.0f
            : ((mold == -INFINITY) ? ((mnew == -INFINITY) ? 1.0f : 0.0f)
                                   : __expf(mold - mnew));
        const bool dead = (mnew == -INFINITY);
        float rsum = 0.f;
        #pragma unroll
        for (int r = 0; r < 16; ++r) {
            float e = dead ? 0.f : __expf(p[r] - mnew);
            p[r] = e;
            rsum += e;
        }
        rsum += __shfl_xor(rsum, 32);
        lrun = lrun * alpha + rsum;
        mrun = mnew;
        if (!defer) {
            #pragma unroll
            for (int dblk = 0; dblk < 4; ++dblk)
                oacc[dblk] = oacc[dblk] * alpha;
        }

        // ---- pack P -> B-frag via shfl_xor(32) cross-half exchange ----
        // lane (hi,l31) word w of pb0 needs kv = hi*8 + 2w,2w+1; pb1: +16.
        // own data: c0=kv(0,1)+4hi, c1=kv(2,3)+4hi, c2=kv(8,9)+4hi, c3=kv(10,11)+4hi
        //           c4..c7 = same +16
        unsigned int c0 = pack2bf(p[0],  p[1]);
        unsigned int c1 = pack2bf(p[2],  p[3]);
        unsigned int c2 = pack2bf(p[4],  p[5]);
        unsigned int c3 = pack2bf(p[6],  p[7]);
        unsigned int c4 = pack2bf(p[8],  p[9]);
        unsigned int c5 = pack2bf(p[10], p[11]);
        unsigned int c6 = pack2bf(p[12], p[13]);
        unsigned int c7 = pack2bf(p[14], p[15]);
        unsigned int o0 = (unsigned int)__shfl_xor((int)c0, 32);
        unsigned int o1 = (unsigned int)__shfl_xor((int)c1, 32);
        unsigned int o2 = (unsigned int)__shfl_xor((int)c2, 32);
        unsigned int o3 = (unsigned int)__shfl_xor((int)c3, 32);
        unsigned int o4 = (unsigned int)__shfl_xor((int)c4, 32);
        unsigned int o5 = (unsigned int)__shfl_xor((int)c5, 32);
        unsigned int o6 = (unsigned int)__shfl_xor((int)c6, 32);
        unsigned int o7 = (unsigned int)__shfl_xor((int)c7, 32);
        uint4v u0, u1;
        u0[0] = hi ? o2 : c0;   // w0: hi0 kv(0,1),  hi1 kv(8,9)
        u0[1] = hi ? o3 : c1;   // w1: hi0 kv(2,3),  hi1 kv(10,11)
        u0[2] = hi ? c2 : o0;   // w2: hi0 kv(4,5),  hi1 kv(12,13)
        u0[3] = hi ? c3 : o1;   // w3: hi0 kv(6,7),  hi1 kv(14,15)
        u1[0] = hi ? o6 : c4;
        u1[1] = hi ? o7 : c5;
        u1[2] = hi ? c6 : o4;
        u1[3] = hi ? c7 : o5;
        short8 pb0 = __builtin_bit_cast(short8, u0);   // kv slice 0..15
        short8 pb1 = __builtin_bit_cast(short8, u1);   // kv slice 16..31

        // ---- PV 32x32: O^T += mfma32(A=V^T, B=P^T) ----
        #pragma unroll
        for (int dblk = 0; dblk < 4; ++dblk) {
            short8 vf0 = *(const short8*)&Vt[cur][dblk * 32 + l31][hi * 8];
            short8 vf1 = *(const short8*)&Vt[cur][dblk * 32 + l31][16 + hi * 8];
            oacc[dblk] = MFMA32(vf0, pb0, oacc[dblk], 0, 0, 0);
            oacc[dblk] = MFMA32(vf1, pb1, oacc[dblk], 0, 0, 0);
        }

        cur ^= 1;
    }
#undef LOAD_TILE

    // ---- epilogue: lane-local normalize, b128 stores ----
    {
        const float inv = 1.0f / lrun;
        float* orow = outg + ((size_t)(qstart + q0 + l31) * HQN + hq) * HD;
        #pragma unroll
        for (int dblk = 0; dblk < 4; ++dblk) {
            #pragma unroll
            for (int rq = 0; rq < 4; ++rq) {
                floatx4 o;
                o[0] = oacc[dblk][4 * rq + 0] * inv;
                o[1] = oacc[dblk][4 * rq + 1] * inv;
                o[2] = oacc[dblk][4 * rq + 2] * inv;
                o[3] = oacc[dblk][4 * rq + 3] * inv;
                *(floatx4*)(orow + dblk * 32 + 8 * rq + 4 * hi) = o;
            }
        }
    }
}

extern "C" void kernel_launch(void* const* d_in, const int* in_sizes, int n_in,
                              void* d_out, int out_size, void* d_ws, size_t ws_size,
                              hipStream_t stream) {
    const float* q  = (const float*)d_in[0];
    const float* k  = (const float*)d_in[1];
    const float* v  = (const float*)d_in[2];
    const int* btp  = (const int*)d_in[3];
    const int* sl   = (const int*)d_in[4];
    const int* qs   = (const int*)d_in[5];
    float* out      = (float*)d_out;

    attn_fwd<<<dim3(NSEQ * HKVN * 8), 256, 0, stream>>>(q, k, v, btp, sl, qs, out);
}

// Round 13
// 79.686 us; speedup vs baseline: 5.3102x; 1.0686x over previous
//
#include <hip/hip_runtime.h>
#include <stdint.h>

typedef __attribute__((ext_vector_type(8))) short short8;
typedef __attribute__((ext_vector_type(4))) float floatx4;
typedef __attribute__((ext_vector_type(16))) float f32x16;
typedef __attribute__((ext_vector_type(4))) unsigned int uint4v;

#define NSEQ 8
#define BLKSZ 16
#define NBLK_PER_SEQ 128
#define HQN 32
#define HKVN 8
#define GQ 4
#define HD 128
#define WINDOW 1024
// SCALE * log2(e): softmax done in exp2 domain (v_exp_f32 is natively 2^x)
#define QSCALE 0.12751744f

#define QB 32       // q rows per block (4 waves = 4 GQA heads share K/V)
#define KVB 64      // kv tile
#define KROW 136    // K lds row stride (bf16), single-buffered
#define VROW 72     // V^T lds row stride, double-buffered

#define MFMA32 __builtin_amdgcn_mfma_f32_32x32x16_bf16

// two f32 -> packed bf16x2 (round-half-up) via one v_perm; low16 = lo, high16 = hi
static __device__ __forceinline__ unsigned int pack2bf(float lo, float hi) {
    unsigned int a = __builtin_bit_cast(unsigned int, lo) + 0x8000u;
    unsigned int b = __builtin_bit_cast(unsigned int, hi) + 0x8000u;
    return __builtin_amdgcn_perm(b, a, 0x07060302u);
}

__global__ __launch_bounds__(256, 2)
void attn_fwd(const float* __restrict__ qg,
              const float* __restrict__ kg,
              const float* __restrict__ vg,
              const int* __restrict__ bt,
              const int* __restrict__ seqlens,
              const int* __restrict__ qsl,
              float* __restrict__ outg)
{
    __shared__ __align__(16) short Klds[KVB][KROW];   // 17408 B (single)
    __shared__ __align__(16) short Vt[2][HD][VROW];   // 36864 B (dbuf) -> 54272 total

    const int tid  = threadIdx.x;
    const int lane = tid & 63;
    const int wave = tid >> 6;
    const int l31  = lane & 31;
    const int hi   = lane >> 5;

    // XCD pinning: consecutive block ids round-robin XCDs -> b&7 = kv head
    const int b  = blockIdx.x;
    const int h  = b & 7;
    const int qt = (b >> 3) & 7;
    const int s  = b >> 6;
    const int q0 = qt * QB;

    const int qstart = qsl[s];
    const int numq   = qsl[s + 1] - qstart;
    const int slen   = seqlens[s];
    const int ctx    = slen - numq;
    const int hq     = h * GQ + wave;

    // ---- Q fragments (B-operand 32x32x16: col=q=l31, k=ks*16+hi*8+j), pre-scaled ----
    short8 qf[8];
    {
        const float* qrow = qg + ((size_t)(qstart + q0 + l31) * HQN + hq) * HD;
        #pragma unroll
        for (int ks = 0; ks < 8; ++ks) {
            floatx4 f0 = *(const floatx4*)(qrow + ks * 16 + hi * 8);
            floatx4 f1 = *(const floatx4*)(qrow + ks * 16 + hi * 8 + 4);
            uint4v w;
            w[0] = pack2bf(f0[0] * QSCALE, f0[1] * QSCALE);
            w[1] = pack2bf(f0[2] * QSCALE, f0[3] * QSCALE);
            w[2] = pack2bf(f1[0] * QSCALE, f1[1] * QSCALE);
            w[3] = pack2bf(f1[2] * QSCALE, f1[3] * QSCALE);
            qf[ks] = __builtin_bit_cast(short8, w);
        }
    }

    // O^T accumulators: oacc[dblk]; lane: q = l31, d = dblk*32 + (r&3) + 8*(r>>2) + 4*hi
    f32x16 oacc[4];
    #pragma unroll
    for (int dblk = 0; dblk < 4; ++dblk)
        #pragma unroll
        for (int i = 0; i < 16; ++i)
            oacc[dblk][i] = 0.f;

    float mrun = -INFINITY, lrun = 0.f;   // in log2 units

    int lo = ctx + q0 - WINDOW + 1; if (lo < 0) lo = 0;
    int hiq = ctx + q0 + QB - 1;    if (hiq > slen - 1) hiq = slen - 1;
    const int t0 = lo / KVB, t1 = hiq / KVB;

    // staging maps
    const int srow = tid >> 3;          // K: kv row 0..31 (+32 for p=1)
    const int sd0  = (tid & 7) * 16;    // K: d offset (floats)
    const int k2   = tid & 15;          // V: kv pair index
    const int d0v  = (tid >> 4) * 8;    // V: d offset (0..120)

    floatx4 fk[8], fv[8];               // raw f32 for next tile (T14 async split)

#define LOAD_HALF(kv0_, p) {                                                         \
        const int kvp = (kv0_) + (p) * 32 + srow;                                    \
        const int blk = bt[s * NBLK_PER_SEQ + (kvp >> 4)];                           \
        const float* src = kg + (((size_t)blk * BLKSZ + (kvp & 15)) * HKVN + h) * HD + sd0; \
        fk[(p)*4+0] = *(const floatx4*)(src);                                        \
        fk[(p)*4+1] = *(const floatx4*)(src + 4);                                    \
        fk[(p)*4+2] = *(const floatx4*)(src + 8);                                    \
        fk[(p)*4+3] = *(const floatx4*)(src + 12);                                   \
        const int kvv = (kv0_) + (p) * 32 + 2 * k2;                                  \
        const int blkv = bt[s * NBLK_PER_SEQ + (kvv >> 4)];                          \
        const float* vsrc = vg + (((size_t)blkv * BLKSZ + (kvv & 15)) * HKVN + h) * HD + d0v; \
        fv[(p)*4+0] = *(const floatx4*)(vsrc);                                       \
        fv[(p)*4+1] = *(const floatx4*)(vsrc + 4);                                   \
        fv[(p)*4+2] = *(const floatx4*)(vsrc + (size_t)HKVN * HD);                   \
        fv[(p)*4+3] = *(const floatx4*)(vsrc + (size_t)HKVN * HD + 4);               \
    }
#define LOAD_TILE(kv0_) { LOAD_HALF(kv0_, 0); LOAD_HALF(kv0_, 1); }

    LOAD_TILE(t0 * KVB);

    for (int t = t0; t <= t1; ++t) {
        const int kv0 = t * KVB;
        const int vb  = t & 1;

        // ---- convert + store tile t (K single, V into dbuf half) ----
        #pragma unroll
        for (int p = 0; p < 2; ++p) {
            const int row = p * 32 + srow;
            uint4v w;
            w[0] = pack2bf(fk[p*4+0][0], fk[p*4+0][1]);
            w[1] = pack2bf(fk[p*4+0][2], fk[p*4+0][3]);
            w[2] = pack2bf(fk[p*4+1][0], fk[p*4+1][1]);
            w[3] = pack2bf(fk[p*4+1][2], fk[p*4+1][3]);
            *(uint4v*)&Klds[row][sd0] = w;
            w[0] = pack2bf(fk[p*4+2][0], fk[p*4+2][1]);
            w[1] = pack2bf(fk[p*4+2][2], fk[p*4+2][3]);
            w[2] = pack2bf(fk[p*4+3][0], fk[p*4+3][1]);
            w[3] = pack2bf(fk[p*4+3][2], fk[p*4+3][3]);
            *(uint4v*)&Klds[row][sd0 + 8] = w;
        }
        #pragma unroll
        for (int p = 0; p < 2; ++p)
            #pragma unroll
            for (int i = 0; i < 8; ++i) {
                // low short = even kv, high = odd kv
                *(unsigned int*)&Vt[vb][d0v + i][p * 32 + 2 * k2] =
                    pack2bf(fv[p*4 + (i >> 2)][i & 3], fv[p*4 + 2 + (i >> 2)][i & 3]);
            }

        // ---- issue next tile's global loads ----
        if (t < t1) LOAD_TILE(kv0 + KVB);

        __syncthreads();   // barrier#1: staged tile visible

        // ---- swapped QK^T 32x32 on both kv-halves ----
        f32x16 sacc0, sacc1;
        #pragma unroll
        for (int i = 0; i < 16; ++i) { sacc0[i] = 0.f; sacc1[i] = 0.f; }
        #pragma unroll
        for (int ks = 0; ks < 8; ++ks) {
            short8 kf0 = *(const short8*)&Klds[l31][ks * 16 + hi * 8];
            short8 kf1 = *(const short8*)&Klds[32 + l31][ks * 16 + hi * 8];
            sacc0 = MFMA32(kf0, qf[ks], sacc0, 0, 0, 0);
            sacc1 = MFMA32(kf1, qf[ks], sacc1, 0, 0, 0);
        }

        __syncthreads();   // barrier#2: all K reads done -> next iter store safe

        // ---- lane-local online softmax over 64 kv (exp2 domain) ----
        const bool interior = (kv0 >= ctx + q0 - (WINDOW - QB)) &&
                              (kv0 + KVB - 1 <= ctx + q0);
        const int qpos = ctx + q0 + l31;
        float p2[2][16];
        float rmax = -INFINITY;
        #pragma unroll
        for (int m2 = 0; m2 < 2; ++m2) {
            #pragma unroll
            for (int r = 0; r < 16; ++r) {
                float x = (m2 == 0) ? sacc0[r] : sacc1[r];
                if (!interior) {
                    const int kpos = kv0 + m2 * 32 + (r & 3) + 4 * hi + 8 * (r >> 2);
                    const bool valid = (kpos <= qpos) && (qpos - kpos < WINDOW);
                    x = valid ? x : -INFINITY;
                }
                p2[m2][r] = x;
                rmax = fmaxf(rmax, x);
            }
        }
        rmax = fmaxf(rmax, __shfl_xor(rmax, 32));
        const float mold = mrun;
        const bool defer = __all(rmax <= mold + 11.0f);   // THR ~ 8 nats in log2 units
        const float mnew = defer ? mold : fmaxf(mold, rmax);
        const float alpha = defer ? 1.0f
            : ((mold == -INFINITY) ? ((mnew == -INFINITY) ? 1.0f : 0.0f)
                                   : exp2f(mold - mnew));
        const bool dead = (mnew == -INFINITY);
        float rsum = 0.f;
        #pragma unroll
        for (int m2 = 0; m2 < 2; ++m2)
            #pragma unroll
            for (int r = 0; r < 16; ++r) {
                float e = dead ? 0.f : exp2f(p2[m2][r] - mnew);
                p2[m2][r] = e;
                rsum += e;
            }
        rsum += __shfl_xor(rsum, 32);
        lrun = lrun * alpha + rsum;
        mrun = mnew;
        if (!defer) {
            #pragma unroll
            for (int dblk = 0; dblk < 4; ++dblk)
                oacc[dblk] = oacc[dblk] * alpha;
        }

        // ---- pack P -> B-frags via shfl_xor(32) exchange (per kv-half) ----
        short8 pb[2][2];
        #pragma unroll
        for (int m2 = 0; m2 < 2; ++m2) {
            unsigned int c0 = pack2bf(p2[m2][0],  p2[m2][1]);
            unsigned int c1 = pack2bf(p2[m2][2],  p2[m2][3]);
            unsigned int c2 = pack2bf(p2[m2][4],  p2[m2][5]);
            unsigned int c3 = pack2bf(p2[m2][6],  p2[m2][7]);
            unsigned int c4 = pack2bf(p2[m2][8],  p2[m2][9]);
            unsigned int c5 = pack2bf(p2[m2][10], p2[m2][11]);
            unsigned int c6 = pack2bf(p2[m2][12], p2[m2][13]);
            unsigned int c7 = pack2bf(p2[m2][14], p2[m2][15]);
            unsigned int o0 = (unsigned int)__shfl_xor((int)c0, 32);
            unsigned int o1 = (unsigned int)__shfl_xor((int)c1, 32);
            unsigned int o2 = (unsigned int)__shfl_xor((int)c2, 32);
            unsigned int o3 = (unsigned int)__shfl_xor((int)c3, 32);
            unsigned int o4 = (unsigned int)__shfl_xor((int)c4, 32);
            unsigned int o5 = (unsigned int)__shfl_xor((int)c5, 32);
            unsigned int o6 = (unsigned int)__shfl_xor((int)c6, 32);
            unsigned int o7 = (unsigned int)__shfl_xor((int)c7, 32);
            uint4v u0, u1;
            u0[0] = hi ? o2 : c0;
            u0[1] = hi ? o3 : c1;
            u0[2] = hi ? c2 : o0;
            u0[3] = hi ? c3 : o1;
            u1[0] = hi ? o6 : c4;
            u1[1] = hi ? o7 : c5;
            u1[2] = hi ? c6 : o4;
            u1[3] = hi ? c7 : o5;
            pb[m2][0] = __builtin_bit_cast(short8, u0);   // kv m2*32 + 0..15
            pb[m2][1] = __builtin_bit_cast(short8, u1);   // kv m2*32 + 16..31
        }

        // ---- PV 32x32: O^T += mfma32(A=V^T, B=P^T), both kv-halves ----
        #pragma unroll
        for (int m2 = 0; m2 < 2; ++m2) {
            #pragma unroll
            for (int dblk = 0; dblk < 4; ++dblk) {
                short8 vf0 = *(const short8*)&Vt[vb][dblk * 32 + l31][m2 * 32 + hi * 8];
                short8 vf1 = *(const short8*)&Vt[vb][dblk * 32 + l31][m2 * 32 + 16 + hi * 8];
                oacc[dblk] = MFMA32(vf0, pb[m2][0], oacc[dblk], 0, 0, 0);
                oacc[dblk] = MFMA32(vf1, pb[m2][1], oacc[dblk], 0, 0, 0);
            }
        }
    }
#undef LOAD_TILE
#undef LOAD_HALF

    // ---- epilogue: lane-local normalize, b128 stores ----
    {
        const float inv = 1.0f / lrun;
        float* orow = outg + ((size_t)(qstart + q0 + l31) * HQN + hq) * HD;
        #pragma unroll
        for (int dblk = 0; dblk < 4; ++dblk) {
            #pragma unroll
            for (int rq = 0; rq < 4; ++rq) {
                floatx4 o;
                o[0] = oacc[dblk][4 * rq + 0] * inv;
                o[1] = oacc[dblk][4 * rq + 1] * inv;
                o[2] = oacc[dblk][4 * rq + 2] * inv;
                o[3] = oacc[dblk][4 * rq + 3] * inv;
                *(floatx4*)(orow + dblk * 32 + 8 * rq + 4 * hi) = o;
            }
        }
    }
}

extern "C" void kernel_launch(void* const* d_in, const int* in_sizes, int n_in,
                              void* d_out, int out_size, void* d_ws, size_t ws_size,
                              hipStream_t stream) {
    const float* q  = (const float*)d_in[0];
    const float* k  = (const float*)d_in[1];
    const float* v  = (const float*)d_in[2];
    const int* btp  = (const int*)d_in[3];
    const int* sl   = (const int*)d_in[4];
    const int* qs   = (const int*)d_in[5];
    float* out      = (float*)d_out;

    attn_fwd<<<dim3(NSEQ * HKVN * 8), 256, 0, stream>>>(q, k, v, btp, sl, qs, out);
}